// Round 3
// baseline (892.925 us; speedup 1.0000x reference)
//
#include <hip/hip_runtime.h>
#include <math.h>

// Problem constants
#define NB    4096   // batch
#define NCEN  2048   // centres
#define DX    32     // feature dim
#define SEG   512    // centres per segment
#define RK    64     // TT rank
#define CAP   64     // max kept centres per (b, segment)
#define NBCAP (NB * CAP)
#define PARTS 4      // list-split factor for inverted stage blocks

// ---------------------------------------------------------------------------
// Select: per (b, seg) e[d] = max(||x||^2+||c||^2-2x.c, 0)*exp(-2 ls).
// Block = 32 b-rows x 1 segment. C tile (64 KB) XOR-swizzled in LDS.
// Row = 8 lanes (b_sub = lane>>3, dc = lane&7), e[64] in registers,
// min/count/prefix via width-8 shuffles. Emits forward lists + histogram.
// Dropped relative mass <= 512*e^-16.5 ~ 3.5e-5 per stage (90x margin at R2).
// ---------------------------------------------------------------------------
__global__ __launch_bounds__(256) void select_kernel(
    const float* __restrict__ X, const float* __restrict__ C,
    const float* __restrict__ LS,
    int* __restrict__ CNT, int* __restrict__ IDX, float* __restrict__ VAL,
    int* __restrict__ HIST)
{
    __shared__ float cs[SEG * 32];   // row d at d*32, float4 col p XOR-swizzled
    __shared__ float xs[32 * 36];
    __shared__ float2 cni[SEG];      // (||c||^2, exp(-2 ls))

    const int tid = threadIdx.x;
    const int b0 = blockIdx.x * 32;
    const int seg = blockIdx.y;

    // stage C (coalesced global, swizzled LDS write)
    #pragma unroll
    for (int p = 0; p < 16; ++p) {
        int f = p * 256 + tid;               // float4 slot 0..4095
        int d = f >> 3, c4 = f & 7;
        int pp = (c4 + (d & 7)) & 7;
        *(float4*)&cs[d * 32 + pp * 4] =
            *(const float4*)&C[((size_t)seg * SEG + d) * DX + c4 * 4];
    }
    // stage X
    {
        int r = tid >> 3, c4 = tid & 7;
        *(float4*)&xs[r * 36 + c4 * 4] =
            *(const float4*)&X[((size_t)(b0 + r)) * DX + c4 * 4];
    }
    __syncthreads();

    // cnorm + inv2 (order of float4s is permutation-invariant for the norm)
    #pragma unroll
    for (int r = 0; r < 2; ++r) {
        int d = tid + r * 256;
        float s = 0.f;
        #pragma unroll
        for (int p = 0; p < 8; ++p) {
            float4 cv = *(const float4*)&cs[d * 32 + p * 4];
            s += cv.x * cv.x + cv.y * cv.y + cv.z * cv.z + cv.w * cv.w;
        }
        cni[d] = make_float2(s, expf(-2.f * LS[seg * SEG + d]));
    }
    __syncthreads();

    const int wave = tid >> 6, lane = tid & 63;
    const int b_sub = lane >> 3, dc = lane & 7;
    const int b = b0 + wave * 8 + b_sub;

    float4 xv[8];
    float xn = 0.f;
    #pragma unroll
    for (int p = 0; p < 8; ++p) {
        xv[p] = *(const float4*)&xs[(wave * 8 + b_sub) * 36 + p * 4];
        xn += xv[p].x * xv[p].x + xv[p].y * xv[p].y +
              xv[p].z * xv[p].z + xv[p].w * xv[p].w;
    }

    float e[64];
    #pragma unroll
    for (int i = 0; i < 64; ++i) {
        const int d = i * 8 + dc;            // d & 7 == dc
        float dot = 0.f;
        #pragma unroll
        for (int mq = 0; mq < 8; ++mq) {
            int pp = (mq + dc) & 7;
            float4 cv = *(const float4*)&cs[d * 32 + pp * 4];
            dot += xv[mq].x * cv.x + xv[mq].y * cv.y +
                   xv[mq].z * cv.z + xv[mq].w * cv.w;
        }
        float2 ci = cni[d];
        e[i] = fmaxf(xn + ci.x - 2.f * dot, 0.f) * ci.y;
    }

    // row min over 64 regs + 8 lanes
    float m = e[0];
    #pragma unroll
    for (int i = 1; i < 64; ++i) m = fminf(m, e[i]);
    m = fminf(m, __shfl_xor(m, 1));
    m = fminf(m, __shfl_xor(m, 2));
    m = fminf(m, __shfl_xor(m, 4));

    // ladder: count at T=16.5 first; tighten only if needed (rare rows)
    int c0 = 0;
    #pragma unroll
    for (int i = 0; i < 64; ++i) c0 += (e[i] <= m + 16.5f) ? 1 : 0;
    c0 += __shfl_xor(c0, 1); c0 += __shfl_xor(c0, 2); c0 += __shfl_xor(c0, 4);

    float Tp;
    if (c0 <= CAP) {
        Tp = 16.5f;
    } else {
        int c1 = 0, c2 = 0, c3 = 0, c4n = 0, c5 = 0;
        #pragma unroll
        for (int i = 0; i < 64; ++i) {
            c1  += (e[i] <= m + 12.f)  ? 1 : 0;
            c2  += (e[i] <= m + 9.f)   ? 1 : 0;
            c3  += (e[i] <= m + 6.f)   ? 1 : 0;
            c4n += (e[i] <= m + 4.f)   ? 1 : 0;
            c5  += (e[i] <= m + 2.f)   ? 1 : 0;
        }
        c1 += __shfl_xor(c1,1); c1 += __shfl_xor(c1,2); c1 += __shfl_xor(c1,4);
        c2 += __shfl_xor(c2,1); c2 += __shfl_xor(c2,2); c2 += __shfl_xor(c2,4);
        c3 += __shfl_xor(c3,1); c3 += __shfl_xor(c3,2); c3 += __shfl_xor(c3,4);
        c4n += __shfl_xor(c4n,1); c4n += __shfl_xor(c4n,2); c4n += __shfl_xor(c4n,4);
        c5 += __shfl_xor(c5,1); c5 += __shfl_xor(c5,2); c5 += __shfl_xor(c5,4);
        if      (c1  <= CAP) Tp = 12.f;
        else if (c2  <= CAP) Tp = 9.f;
        else if (c3  <= CAP) Tp = 6.f;
        else if (c4n <= CAP) Tp = 4.f;
        else if (c5  <= CAP) Tp = 2.f;
        else                 Tp = 0.75f;
    }
    const float thr = m + Tp;

    // width-8 exclusive prefix of local pass-counts
    int loc = 0;
    #pragma unroll
    for (int i = 0; i < 64; ++i) loc += (e[i] <= thr) ? 1 : 0;
    int incl = loc;
    {
        int t;
        t = __shfl_up(incl, 1, 8); if ((lane & 7) >= 1) incl += t;
        t = __shfl_up(incl, 2, 8); if ((lane & 7) >= 2) incl += t;
        t = __shfl_up(incl, 4, 8); if ((lane & 7) >= 4) incl += t;
    }
    const int excl = incl - loc;
    const int total = __shfl(incl, 7, 8);

    const int base = (b * 4 + seg) * CAP;
    int slot = excl;
    #pragma unroll
    for (int i = 0; i < 64; ++i) {
        if (e[i] <= thr) {
            if (slot < CAP) {
                IDX[base + slot] = i * 8 + dc;
                VAL[base + slot] = expf(-e[i]);
                atomicAdd(&HIST[seg * SEG + i * 8 + dc], 1);
            }
            slot++;
        }
    }
    if (dc == 0) CNT[b * 4 + seg] = total < CAP ? total : CAP;
}

// ---------------------------------------------------------------------------
// Scan: per segment, exclusive prefix over 512 bins (one wave per segment).
// ---------------------------------------------------------------------------
__global__ __launch_bounds__(64) void scan_kernel(
    const int* __restrict__ HIST, int* __restrict__ OFFS, int* __restrict__ CUR)
{
    const int seg = blockIdx.x, lane = threadIdx.x;
    int h[8], s = 0;
    #pragma unroll
    for (int i = 0; i < 8; ++i) { h[i] = HIST[seg * SEG + lane * 8 + i]; s += h[i]; }
    int incl = s, t;
    t = __shfl_up(incl, 1, 64);  if (lane >= 1)  incl += t;
    t = __shfl_up(incl, 2, 64);  if (lane >= 2)  incl += t;
    t = __shfl_up(incl, 4, 64);  if (lane >= 4)  incl += t;
    t = __shfl_up(incl, 8, 64);  if (lane >= 8)  incl += t;
    t = __shfl_up(incl, 16, 64); if (lane >= 16) incl += t;
    t = __shfl_up(incl, 32, 64); if (lane >= 32) incl += t;
    int run = incl - s;
    #pragma unroll
    for (int i = 0; i < 8; ++i) {
        OFFS[seg * SEG + lane * 8 + i] = run;
        CUR[seg * SEG + lane * 8 + i] = run;
        run += h[i];
    }
}

// ---------------------------------------------------------------------------
// Scatter: forward lists -> per-d inverted lists (segs 1..3 only).
// One wave per (b, seg); lane t handles entry t (cnt <= 64).
// ---------------------------------------------------------------------------
__global__ __launch_bounds__(256) void scatter_kernel(
    const int* __restrict__ CNT, const int* __restrict__ IDX,
    const float* __restrict__ VAL, int* __restrict__ CUR,
    int* __restrict__ BL, float* __restrict__ PV)
{
    const int tid = threadIdx.x;
    const int b = blockIdx.x * 4 + (tid >> 6);
    const int seg = blockIdx.y + 1;
    const int lane = tid & 63;
    const int cnt = CNT[b * 4 + seg];
    if (lane < cnt) {
        const int base = (b * 4 + seg) * CAP;
        int d = IDX[base + lane];
        float v = VAL[base + lane];
        int pos = atomicAdd(&CUR[seg * SEG + d], 1);
        BL[(size_t)seg * NBCAP + pos] = b;
        PV[(size_t)seg * NBCAP + pos] = v;
    }
}

// ---------------------------------------------------------------------------
// R0[b,i] = sum_t val_t * G0[d_t,i]. One wave per b (4 waves/block).
// ---------------------------------------------------------------------------
__global__ __launch_bounds__(256) void r0_sparse(
    const float* __restrict__ G0,
    const int* __restrict__ CNT, const int* __restrict__ IDX,
    const float* __restrict__ VAL, float* __restrict__ R0v)
{
    const int tid = threadIdx.x;
    const int b = blockIdx.x * 4 + (tid >> 6);
    const int lane = tid & 63;
    const int tg = lane >> 4, iq = lane & 15;
    const int cnt = CNT[b * 4];
    const int base = b * 4 * CAP;
    float4 acc = make_float4(0.f, 0.f, 0.f, 0.f);
    for (int t = tg; t < cnt; t += 4) {
        int d = IDX[base + t];
        float v = VAL[base + t];
        float4 g = *(const float4*)&G0[(size_t)d * RK + iq * 4];
        acc.x += v * g.x; acc.y += v * g.y; acc.z += v * g.z; acc.w += v * g.w;
    }
    acc.x += __shfl_xor(acc.x, 16); acc.y += __shfl_xor(acc.y, 16);
    acc.z += __shfl_xor(acc.z, 16); acc.w += __shfl_xor(acc.w, 16);
    acc.x += __shfl_xor(acc.x, 32); acc.y += __shfl_xor(acc.y, 32);
    acc.z += __shfl_xor(acc.z, 32); acc.w += __shfl_xor(acc.w, 32);
    if (tg == 0) *(float4*)&R0v[(size_t)b * RK + iq * 4] = acc;
}

// ---------------------------------------------------------------------------
// Inverted stage: block = (d, part). Gd = G[:,d,:] in LDS once; chunks of
// CH entries from d's (b, phi) list; thread (eg, jq) computes
// tmp[j] = sum_k tin[b_eg,k]*Gd[k,j]; atomicAdd phi*tmp into TOUT[b_eg].
// ---------------------------------------------------------------------------
template <int NOUT>
__global__ __launch_bounds__(256) void inv_stage(
    const float* __restrict__ TIN, const float* __restrict__ G,
    const int* __restrict__ HISTs, const int* __restrict__ OFFSs,
    const int* __restrict__ BLs, const float* __restrict__ PVs,
    float* __restrict__ TOUT)
{
    constexpr int JL = NOUT / 4;             // j-quad lanes per entry (16/8)
    constexpr int CH = 256 / JL;             // entries per chunk (16/32)
    __shared__ float gd[64 * NOUT];
    __shared__ float tins[CH * 68];

    const int tid = threadIdx.x;
    const int d = blockIdx.x, part = blockIdx.y;
    const int len = HISTs[d];
    if (len == 0) return;
    const int off0 = OFFSs[d];

    #pragma unroll
    for (int p = 0; p < (64 * NOUT / 4) / 256; ++p) {
        int f = p * 256 + tid;
        int k = f / (NOUT / 4), jj = f % (NOUT / 4);
        *(float4*)&gd[k * NOUT + jj * 4] =
            *(const float4*)&G[((size_t)k * SEG + d) * NOUT + jj * 4];
    }

    const int eg = tid / JL, jq = tid % JL;

    for (int c = part; c * CH < len; c += PARTS) {
        __syncthreads();   // gd ready (1st iter); prev chunk's readers done
        const int eidx = c * CH + eg;
        const bool valid = eidx < len;
        const int brow = valid ? BLs[off0 + eidx] : 0;
        #pragma unroll
        for (int q = 0; q < 16 / JL; ++q) {
            int c4 = jq + q * JL;
            *(float4*)&tins[eg * 68 + c4 * 4] =
                *(const float4*)&TIN[(size_t)brow * RK + c4 * 4];
        }
        __syncthreads();

        float4 acc = make_float4(0.f, 0.f, 0.f, 0.f);
        #pragma unroll 8
        for (int k = 0; k < 64; ++k) {
            float tv = tins[eg * 68 + k];
            float4 gv = *(const float4*)&gd[k * NOUT + jq * 4];
            acc.x += tv * gv.x; acc.y += tv * gv.y;
            acc.z += tv * gv.z; acc.w += tv * gv.w;
        }
        if (valid) {
            float ph = PVs[off0 + eidx];
            float* dst = &TOUT[(size_t)brow * NOUT + jq * 4];
            atomicAdd(dst + 0, ph * acc.x);
            atomicAdd(dst + 1, ph * acc.y);
            atomicAdd(dst + 2, ph * acc.z);
            atomicAdd(dst + 3, ph * acc.w);
        }
    }
}

// ---------------------------------------------------------------------------
extern "C" void kernel_launch(void* const* d_in, const int* in_sizes, int n_in,
                              void* d_out, int out_size, void* d_ws, size_t ws_size,
                              hipStream_t stream)
{
    const float* X  = (const float*)d_in[0];
    const float* C  = (const float*)d_in[1];
    const float* LS = (const float*)d_in[2];
    const float* G0 = (const float*)d_in[3];
    const float* G1 = (const float*)d_in[4];
    const float* G2 = (const float*)d_in[5];
    const float* G3 = (const float*)d_in[6];
    float* out = (float*)d_out;

    char* ws = (char*)d_ws;
    size_t o = 0;
    int*   CNT  = (int*)(ws + o);  o += (size_t)NB * 4 * 4;          // 64 KB
    int*   IDX  = (int*)(ws + o);  o += (size_t)NB * 4 * CAP * 4;    // 4 MB
    float* VAL  = (float*)(ws + o); o += (size_t)NB * 4 * CAP * 4;   // 4 MB
    int*   HIST = (int*)(ws + o);  o += 4 * SEG * 4;                 // 8 KB
    int*   OFFS = (int*)(ws + o);  o += 4 * SEG * 4;                 // 8 KB
    int*   CUR  = (int*)(ws + o);  o += 4 * SEG * 4;                 // 8 KB
    int*   BL   = (int*)(ws + o);  o += (size_t)4 * NBCAP * 4;       // 4 MB
    float* PV   = (float*)(ws + o); o += (size_t)4 * NBCAP * 4;      // 4 MB
    float* R0v  = (float*)(ws + o); o += (size_t)NB * RK * 4;        // 1 MB
    float* t1   = (float*)(ws + o); o += (size_t)NB * RK * 4;        // 1 MB
    float* t2   = (float*)(ws + o); o += (size_t)NB * RK * 4;        // 1 MB

    hipMemsetAsync(HIST, 0, 4 * SEG * 4, stream);
    hipMemsetAsync(t1, 0, (size_t)NB * RK * 4, stream);
    hipMemsetAsync(t2, 0, (size_t)NB * RK * 4, stream);
    hipMemsetAsync(d_out, 0, (size_t)out_size * sizeof(float), stream);

    select_kernel<<<dim3(NB / 32, 4), 256, 0, stream>>>(X, C, LS, CNT, IDX, VAL, HIST);
    scan_kernel<<<4, 64, 0, stream>>>(HIST, OFFS, CUR);
    scatter_kernel<<<dim3(NB / 4, 3), 256, 0, stream>>>(CNT, IDX, VAL, CUR, BL, PV);
    r0_sparse<<<NB / 4, 256, 0, stream>>>(G0, CNT, IDX, VAL, R0v);
    inv_stage<64><<<dim3(SEG, PARTS), 256, 0, stream>>>(
        R0v, G1, HIST + SEG, OFFS + SEG, BL + (size_t)NBCAP, PV + (size_t)NBCAP, t1);
    inv_stage<64><<<dim3(SEG, PARTS), 256, 0, stream>>>(
        t1, G2, HIST + 2 * SEG, OFFS + 2 * SEG, BL + (size_t)2 * NBCAP, PV + (size_t)2 * NBCAP, t2);
    inv_stage<32><<<dim3(SEG, PARTS), 256, 0, stream>>>(
        t2, G3, HIST + 3 * SEG, OFFS + 3 * SEG, BL + (size_t)3 * NBCAP, PV + (size_t)3 * NBCAP, out);
}

// Round 4
// 663.083 us; speedup vs baseline: 1.3466x; 1.3466x over previous
//
#include <hip/hip_runtime.h>
#include <math.h>

// Problem constants
#define NB    4096   // batch
#define NCEN  2048   // centres
#define DX    32     // feature dim
#define SEG   512    // centres per segment
#define RK    64     // TT rank
#define CAP   64     // max kept centres per (b, segment)
#define NBCAP (NB * CAP)
#define PARTS 4      // list-split factor for inverted stage blocks

// ---------------------------------------------------------------------------
// Select: per (b, seg) e[d] = max(||x||^2+||c||^2-2x.c, 0)*exp(-2 ls).
// Block = 32 b-rows x 1 segment. C tile (64 KB) XOR-swizzled in LDS.
// Row = 8 lanes, e[64] in registers, min/count/prefix via width-8 shuffles.
// Dropped relative mass <= 512*e^-16.5 ~ 3.5e-5 per stage (90x margin).
// ---------------------------------------------------------------------------
__global__ __launch_bounds__(256) void select_kernel(
    const float* __restrict__ X, const float* __restrict__ C,
    const float* __restrict__ LS,
    int* __restrict__ CNT, int* __restrict__ IDX, float* __restrict__ VAL,
    int* __restrict__ HIST)
{
    __shared__ float cs[SEG * 32];
    __shared__ float xs[32 * 36];
    __shared__ float2 cni[SEG];

    const int tid = threadIdx.x;
    const int b0 = blockIdx.x * 32;
    const int seg = blockIdx.y;

    #pragma unroll
    for (int p = 0; p < 16; ++p) {
        int f = p * 256 + tid;
        int d = f >> 3, c4 = f & 7;
        int pp = (c4 + (d & 7)) & 7;
        *(float4*)&cs[d * 32 + pp * 4] =
            *(const float4*)&C[((size_t)seg * SEG + d) * DX + c4 * 4];
    }
    {
        int r = tid >> 3, c4 = tid & 7;
        *(float4*)&xs[r * 36 + c4 * 4] =
            *(const float4*)&X[((size_t)(b0 + r)) * DX + c4 * 4];
    }
    __syncthreads();

    #pragma unroll
    for (int r = 0; r < 2; ++r) {
        int d = tid + r * 256;
        float s = 0.f;
        #pragma unroll
        for (int p = 0; p < 8; ++p) {
            float4 cv = *(const float4*)&cs[d * 32 + p * 4];
            s += cv.x * cv.x + cv.y * cv.y + cv.z * cv.z + cv.w * cv.w;
        }
        cni[d] = make_float2(s, expf(-2.f * LS[seg * SEG + d]));
    }
    __syncthreads();

    const int wave = tid >> 6, lane = tid & 63;
    const int b_sub = lane >> 3, dc = lane & 7;
    const int b = b0 + wave * 8 + b_sub;

    float4 xv[8];
    float xn = 0.f;
    #pragma unroll
    for (int p = 0; p < 8; ++p) {
        xv[p] = *(const float4*)&xs[(wave * 8 + b_sub) * 36 + p * 4];
        xn += xv[p].x * xv[p].x + xv[p].y * xv[p].y +
              xv[p].z * xv[p].z + xv[p].w * xv[p].w;
    }

    float e[64];
    #pragma unroll
    for (int i = 0; i < 64; ++i) {
        const int d = i * 8 + dc;
        float dot = 0.f;
        #pragma unroll
        for (int mq = 0; mq < 8; ++mq) {
            int pp = (mq + dc) & 7;
            float4 cv = *(const float4*)&cs[d * 32 + pp * 4];
            dot += xv[mq].x * cv.x + xv[mq].y * cv.y +
                   xv[mq].z * cv.z + xv[mq].w * cv.w;
        }
        float2 ci = cni[d];
        e[i] = fmaxf(xn + ci.x - 2.f * dot, 0.f) * ci.y;
    }

    float m = e[0];
    #pragma unroll
    for (int i = 1; i < 64; ++i) m = fminf(m, e[i]);
    m = fminf(m, __shfl_xor(m, 1));
    m = fminf(m, __shfl_xor(m, 2));
    m = fminf(m, __shfl_xor(m, 4));

    int c0 = 0;
    #pragma unroll
    for (int i = 0; i < 64; ++i) c0 += (e[i] <= m + 16.5f) ? 1 : 0;
    c0 += __shfl_xor(c0, 1); c0 += __shfl_xor(c0, 2); c0 += __shfl_xor(c0, 4);

    float Tp;
    if (c0 <= CAP) {
        Tp = 16.5f;
    } else {
        int c1 = 0, c2 = 0, c3 = 0, c4n = 0, c5 = 0;
        #pragma unroll
        for (int i = 0; i < 64; ++i) {
            c1  += (e[i] <= m + 12.f)  ? 1 : 0;
            c2  += (e[i] <= m + 9.f)   ? 1 : 0;
            c3  += (e[i] <= m + 6.f)   ? 1 : 0;
            c4n += (e[i] <= m + 4.f)   ? 1 : 0;
            c5  += (e[i] <= m + 2.f)   ? 1 : 0;
        }
        c1 += __shfl_xor(c1,1); c1 += __shfl_xor(c1,2); c1 += __shfl_xor(c1,4);
        c2 += __shfl_xor(c2,1); c2 += __shfl_xor(c2,2); c2 += __shfl_xor(c2,4);
        c3 += __shfl_xor(c3,1); c3 += __shfl_xor(c3,2); c3 += __shfl_xor(c3,4);
        c4n += __shfl_xor(c4n,1); c4n += __shfl_xor(c4n,2); c4n += __shfl_xor(c4n,4);
        c5 += __shfl_xor(c5,1); c5 += __shfl_xor(c5,2); c5 += __shfl_xor(c5,4);
        if      (c1  <= CAP) Tp = 12.f;
        else if (c2  <= CAP) Tp = 9.f;
        else if (c3  <= CAP) Tp = 6.f;
        else if (c4n <= CAP) Tp = 4.f;
        else if (c5  <= CAP) Tp = 2.f;
        else                 Tp = 0.75f;
    }
    const float thr = m + Tp;

    int loc = 0;
    #pragma unroll
    for (int i = 0; i < 64; ++i) loc += (e[i] <= thr) ? 1 : 0;
    int incl = loc;
    {
        int t;
        t = __shfl_up(incl, 1, 8); if ((lane & 7) >= 1) incl += t;
        t = __shfl_up(incl, 2, 8); if ((lane & 7) >= 2) incl += t;
        t = __shfl_up(incl, 4, 8); if ((lane & 7) >= 4) incl += t;
    }
    const int excl = incl - loc;
    const int total = __shfl(incl, 7, 8);

    const int base = (b * 4 + seg) * CAP;
    int slot = excl;
    #pragma unroll
    for (int i = 0; i < 64; ++i) {
        if (e[i] <= thr) {
            if (slot < CAP) {
                IDX[base + slot] = i * 8 + dc;
                VAL[base + slot] = expf(-e[i]);
                atomicAdd(&HIST[seg * SEG + i * 8 + dc], 1);
            }
            slot++;
        }
    }
    if (dc == 0) CNT[b * 4 + seg] = total < CAP ? total : CAP;
}

// ---------------------------------------------------------------------------
// Scan: per segment, exclusive prefix over 512 bins (one wave per segment).
// ---------------------------------------------------------------------------
__global__ __launch_bounds__(64) void scan_kernel(
    const int* __restrict__ HIST, int* __restrict__ OFFS, int* __restrict__ CUR)
{
    const int seg = blockIdx.x, lane = threadIdx.x;
    int h[8], s = 0;
    #pragma unroll
    for (int i = 0; i < 8; ++i) { h[i] = HIST[seg * SEG + lane * 8 + i]; s += h[i]; }
    int incl = s, t;
    t = __shfl_up(incl, 1, 64);  if (lane >= 1)  incl += t;
    t = __shfl_up(incl, 2, 64);  if (lane >= 2)  incl += t;
    t = __shfl_up(incl, 4, 64);  if (lane >= 4)  incl += t;
    t = __shfl_up(incl, 8, 64);  if (lane >= 8)  incl += t;
    t = __shfl_up(incl, 16, 64); if (lane >= 16) incl += t;
    t = __shfl_up(incl, 32, 64); if (lane >= 32) incl += t;
    int run = incl - s;
    #pragma unroll
    for (int i = 0; i < 8; ++i) {
        OFFS[seg * SEG + lane * 8 + i] = run;
        CUR[seg * SEG + lane * 8 + i] = run;
        run += h[i];
    }
}

// ---------------------------------------------------------------------------
// Scatter: forward lists -> per-d inverted lists (segs 1..3), recording
// each forward entry's inverted position in POS for the owner-writes gather.
// ---------------------------------------------------------------------------
__global__ __launch_bounds__(256) void scatter_kernel(
    const int* __restrict__ CNT, const int* __restrict__ IDX,
    const float* __restrict__ VAL, int* __restrict__ CUR,
    int* __restrict__ BL, float* __restrict__ PV, int* __restrict__ POS)
{
    const int tid = threadIdx.x;
    const int b = blockIdx.x * 4 + (tid >> 6);
    const int seg = blockIdx.y + 1;
    const int lane = tid & 63;
    const int cnt = CNT[b * 4 + seg];
    if (lane < cnt) {
        const int base = (b * 4 + seg) * CAP;
        int d = IDX[base + lane];
        float v = VAL[base + lane];
        int pos = atomicAdd(&CUR[seg * SEG + d], 1);   // seg-local position
        BL[(size_t)seg * NBCAP + pos] = b;
        PV[(size_t)seg * NBCAP + pos] = v;
        POS[base + lane] = pos;
    }
}

// ---------------------------------------------------------------------------
// R0[b,i] = sum_t val_t * G0[d_t,i]. One wave per b (4 waves/block).
// ---------------------------------------------------------------------------
__global__ __launch_bounds__(256) void r0_sparse(
    const float* __restrict__ G0,
    const int* __restrict__ CNT, const int* __restrict__ IDX,
    const float* __restrict__ VAL, float* __restrict__ R0v)
{
    const int tid = threadIdx.x;
    const int b = blockIdx.x * 4 + (tid >> 6);
    const int lane = tid & 63;
    const int tg = lane >> 4, iq = lane & 15;
    const int cnt = CNT[b * 4];
    const int base = b * 4 * CAP;
    float4 acc = make_float4(0.f, 0.f, 0.f, 0.f);
    for (int t = tg; t < cnt; t += 4) {
        int d = IDX[base + t];
        float v = VAL[base + t];
        float4 g = *(const float4*)&G0[(size_t)d * RK + iq * 4];
        acc.x += v * g.x; acc.y += v * g.y; acc.z += v * g.z; acc.w += v * g.w;
    }
    acc.x += __shfl_xor(acc.x, 16); acc.y += __shfl_xor(acc.y, 16);
    acc.z += __shfl_xor(acc.z, 16); acc.w += __shfl_xor(acc.w, 16);
    acc.x += __shfl_xor(acc.x, 32); acc.y += __shfl_xor(acc.y, 32);
    acc.z += __shfl_xor(acc.z, 32); acc.w += __shfl_xor(acc.w, 32);
    if (tg == 0) *(float4*)&R0v[(size_t)b * RK + iq * 4] = acc;
}

// ---------------------------------------------------------------------------
// Inverted stage (no atomics): block = (d, part). Gd = G[:,d,:] in LDS once.
// Per entry: CONTRIB[pos][j] = phi * sum_k tin[b,k]*Gd[k,j]  (streaming store)
// ---------------------------------------------------------------------------
template <int NOUT>
__global__ __launch_bounds__(256) void inv_stage(
    const float* __restrict__ TIN, const float* __restrict__ G,
    const int* __restrict__ HISTs, const int* __restrict__ OFFSs,
    const int* __restrict__ BLs, const float* __restrict__ PVs,
    float* __restrict__ CONTRIB)
{
    constexpr int JL = NOUT / 4;             // j-quad lanes per entry (16/8)
    constexpr int CH = 256 / JL;             // entries per chunk (16/32)
    __shared__ float gd[64 * NOUT];
    __shared__ float tins[CH * 68];

    const int tid = threadIdx.x;
    const int d = blockIdx.x, part = blockIdx.y;
    const int len = HISTs[d];
    if (len == 0) return;
    const int off0 = OFFSs[d];

    #pragma unroll
    for (int p = 0; p < (64 * NOUT / 4) / 256; ++p) {
        int f = p * 256 + tid;
        int k = f / (NOUT / 4), jj = f % (NOUT / 4);
        *(float4*)&gd[k * NOUT + jj * 4] =
            *(const float4*)&G[((size_t)k * SEG + d) * NOUT + jj * 4];
    }

    const int eg = tid / JL, jq = tid % JL;

    for (int c = part; c * CH < len; c += PARTS) {
        __syncthreads();
        const int eidx = c * CH + eg;
        const bool valid = eidx < len;
        const int brow = valid ? BLs[off0 + eidx] : 0;
        #pragma unroll
        for (int q = 0; q < 16 / JL; ++q) {
            int c4 = jq + q * JL;
            *(float4*)&tins[eg * 68 + c4 * 4] =
                *(const float4*)&TIN[(size_t)brow * RK + c4 * 4];
        }
        __syncthreads();

        float4 acc = make_float4(0.f, 0.f, 0.f, 0.f);
        #pragma unroll 8
        for (int k = 0; k < 64; ++k) {
            float tv = tins[eg * 68 + k];
            float4 gv = *(const float4*)&gd[k * NOUT + jq * 4];
            acc.x += tv * gv.x; acc.y += tv * gv.y;
            acc.z += tv * gv.z; acc.w += tv * gv.w;
        }
        if (valid) {
            float ph = PVs[off0 + eidx];
            float4 v = make_float4(ph * acc.x, ph * acc.y, ph * acc.z, ph * acc.w);
            *(float4*)&CONTRIB[((size_t)(off0 + eidx)) * NOUT + jq * 4] = v;
        }
    }
}

// ---------------------------------------------------------------------------
// Gather (owner-writes): tout[b,j] = sum_{t<cnt} CONTRIB[POS[b,t]][j].
// One wave per b (4 waves/block). Deterministic per-b sum order.
// ---------------------------------------------------------------------------
template <int NOUT>
__global__ __launch_bounds__(256) void gather_kernel(
    const int* __restrict__ CNT, const int* __restrict__ POS,
    const float* __restrict__ CONTRIB, float* __restrict__ TOUT, int seg)
{
    constexpr int JL = NOUT / 4;             // 16 or 8
    constexpr int TG = 64 / JL;              // 4 or 8
    const int tid = threadIdx.x;
    const int b = blockIdx.x * 4 + (tid >> 6);
    const int lane = tid & 63;
    const int tg = lane / JL, iq = lane % JL;
    const int cnt = CNT[b * 4 + seg];
    const int base = (b * 4 + seg) * CAP;
    float4 acc = make_float4(0.f, 0.f, 0.f, 0.f);
    for (int t = tg; t < cnt; t += TG) {
        int pos = POS[base + t];
        float4 v = *(const float4*)&CONTRIB[(size_t)pos * NOUT + iq * 4];
        acc.x += v.x; acc.y += v.y; acc.z += v.z; acc.w += v.w;
    }
    #pragma unroll
    for (int off = JL; off < 64; off <<= 1) {
        acc.x += __shfl_xor(acc.x, off); acc.y += __shfl_xor(acc.y, off);
        acc.z += __shfl_xor(acc.z, off); acc.w += __shfl_xor(acc.w, off);
    }
    if (tg == 0) *(float4*)&TOUT[(size_t)b * NOUT + iq * 4] = acc;
}

// ---------------------------------------------------------------------------
extern "C" void kernel_launch(void* const* d_in, const int* in_sizes, int n_in,
                              void* d_out, int out_size, void* d_ws, size_t ws_size,
                              hipStream_t stream)
{
    const float* X  = (const float*)d_in[0];
    const float* C  = (const float*)d_in[1];
    const float* LS = (const float*)d_in[2];
    const float* G0 = (const float*)d_in[3];
    const float* G1 = (const float*)d_in[4];
    const float* G2 = (const float*)d_in[5];
    const float* G3 = (const float*)d_in[6];
    float* out = (float*)d_out;

    char* ws = (char*)d_ws;
    size_t o = 0;
    int*   CNT  = (int*)(ws + o);   o += (size_t)NB * 4 * 4;          // 64 KB
    int*   IDX  = (int*)(ws + o);   o += (size_t)NB * 4 * CAP * 4;    // 4 MB
    float* VAL  = (float*)(ws + o); o += (size_t)NB * 4 * CAP * 4;    // 4 MB
    int*   POS  = (int*)(ws + o);   o += (size_t)NB * 4 * CAP * 4;    // 4 MB
    int*   HIST = (int*)(ws + o);   o += 4 * SEG * 4;                 // 8 KB
    int*   OFFS = (int*)(ws + o);   o += 4 * SEG * 4;                 // 8 KB
    int*   CUR  = (int*)(ws + o);   o += 4 * SEG * 4;                 // 8 KB
    int*   BL   = (int*)(ws + o);   o += (size_t)4 * NBCAP * 4;       // 4 MB
    float* PV   = (float*)(ws + o); o += (size_t)4 * NBCAP * 4;       // 4 MB
    float* CONTRIB = (float*)(ws + o); o += (size_t)NBCAP * RK * 4;   // 16 MB
    float* R0v  = (float*)(ws + o); o += (size_t)NB * RK * 4;         // 1 MB
    float* t1   = (float*)(ws + o); o += (size_t)NB * RK * 4;         // 1 MB
    float* t2   = (float*)(ws + o); o += (size_t)NB * RK * 4;         // 1 MB

    hipMemsetAsync(HIST, 0, 4 * SEG * 4, stream);

    select_kernel<<<dim3(NB / 32, 4), 256, 0, stream>>>(X, C, LS, CNT, IDX, VAL, HIST);
    scan_kernel<<<4, 64, 0, stream>>>(HIST, OFFS, CUR);
    scatter_kernel<<<dim3(NB / 4, 3), 256, 0, stream>>>(CNT, IDX, VAL, CUR, BL, PV, POS);
    r0_sparse<<<NB / 4, 256, 0, stream>>>(G0, CNT, IDX, VAL, R0v);

    inv_stage<64><<<dim3(SEG, PARTS), 256, 0, stream>>>(
        R0v, G1, HIST + SEG, OFFS + SEG, BL + (size_t)NBCAP, PV + (size_t)NBCAP, CONTRIB);
    gather_kernel<64><<<NB / 4, 256, 0, stream>>>(CNT, POS, CONTRIB, t1, 1);

    inv_stage<64><<<dim3(SEG, PARTS), 256, 0, stream>>>(
        t1, G2, HIST + 2 * SEG, OFFS + 2 * SEG, BL + (size_t)2 * NBCAP, PV + (size_t)2 * NBCAP, CONTRIB);
    gather_kernel<64><<<NB / 4, 256, 0, stream>>>(CNT, POS, CONTRIB, t2, 2);

    inv_stage<32><<<dim3(SEG, PARTS), 256, 0, stream>>>(
        t2, G3, HIST + 3 * SEG, OFFS + 3 * SEG, BL + (size_t)3 * NBCAP, PV + (size_t)3 * NBCAP, CONTRIB);
    gather_kernel<32><<<NB / 4, 256, 0, stream>>>(CNT, POS, CONTRIB, out, 3);
}

// Round 6
// 641.149 us; speedup vs baseline: 1.3927x; 1.0342x over previous
//
#include <hip/hip_runtime.h>
#include <math.h>

// Problem constants
#define NB    4096   // batch
#define NCEN  2048   // centres
#define DX    32     // feature dim
#define SEG   512    // centres per segment
#define RK    64     // TT rank
#define CAP   64     // max kept centres per (b, segment)
#define NBCAP (NB * CAP)

static __device__ __forceinline__ int wave_sum_i(int v) {
    v += __shfl_xor(v, 1);  v += __shfl_xor(v, 2);  v += __shfl_xor(v, 4);
    v += __shfl_xor(v, 8);  v += __shfl_xor(v, 16); v += __shfl_xor(v, 32);
    return v;
}
static __device__ __forceinline__ float wave_min_f(float v) {
    v = fminf(v, __shfl_xor(v, 1));  v = fminf(v, __shfl_xor(v, 2));
    v = fminf(v, __shfl_xor(v, 4));  v = fminf(v, __shfl_xor(v, 8));
    v = fminf(v, __shfl_xor(v, 16)); v = fminf(v, __shfl_xor(v, 32));
    return v;
}

// ---------------------------------------------------------------------------
// Pass A: E[b,d] = max(||x||^2+||c||^2-2 x.c, 0) * exp(-2 ls_d)
// Register-tiled GEMM: 64x64 tile, 256 threads, 4bx4d per thread, K=32.
// Also zeroes HIST (blocks with blockIdx.y==0; rowselect runs next kernel).
// ---------------------------------------------------------------------------
__global__ __launch_bounds__(256) void e_gemm(
    const float* __restrict__ X, const float* __restrict__ C,
    const float* __restrict__ LS, float* __restrict__ E, int* __restrict__ HIST)
{
    __shared__ float XT[32 * 68];    // [k][b], stride 68
    __shared__ float CT[32 * 68];    // [k][d]
    __shared__ float xn[64];
    __shared__ float2 cni[64];       // (||c||^2, exp(-2 ls))

    const int tid = threadIdx.x;
    const int d0 = blockIdx.x * 64, b0 = blockIdx.y * 64;

    if (blockIdx.y == 0 && tid < 64) HIST[d0 + tid] = 0;

    #pragma unroll
    for (int p = 0; p < 2; ++p) {
        int f = p * 256 + tid;               // 0..511
        int r = f >> 3, c4 = (f & 7) * 4;
        float4 xv = *(const float4*)&X[(size_t)(b0 + r) * DX + c4];
        XT[(c4 + 0) * 68 + r] = xv.x; XT[(c4 + 1) * 68 + r] = xv.y;
        XT[(c4 + 2) * 68 + r] = xv.z; XT[(c4 + 3) * 68 + r] = xv.w;
        float4 cv = *(const float4*)&C[(size_t)(d0 + r) * DX + c4];
        CT[(c4 + 0) * 68 + r] = cv.x; CT[(c4 + 1) * 68 + r] = cv.y;
        CT[(c4 + 2) * 68 + r] = cv.z; CT[(c4 + 3) * 68 + r] = cv.w;
    }
    __syncthreads();

    if (tid < 64) {
        float s = 0.f;
        for (int k = 0; k < 32; ++k) { float v = XT[k * 68 + tid]; s += v * v; }
        xn[tid] = s;
    } else if (tid < 128) {
        int d = tid - 64;
        float s = 0.f;
        for (int k = 0; k < 32; ++k) { float v = CT[k * 68 + d]; s += v * v; }
        cni[d] = make_float2(s, expf(-2.f * LS[d0 + d]));
    }
    __syncthreads();

    const int ty = tid >> 4, tx = tid & 15;
    float acc[4][4] = {};
    #pragma unroll 8
    for (int k = 0; k < 32; ++k) {
        float4 xv = *(const float4*)&XT[k * 68 + ty * 4];
        float4 cv = *(const float4*)&CT[k * 68 + tx * 4];
        acc[0][0] += xv.x * cv.x; acc[0][1] += xv.x * cv.y;
        acc[0][2] += xv.x * cv.z; acc[0][3] += xv.x * cv.w;
        acc[1][0] += xv.y * cv.x; acc[1][1] += xv.y * cv.y;
        acc[1][2] += xv.y * cv.z; acc[1][3] += xv.y * cv.w;
        acc[2][0] += xv.z * cv.x; acc[2][1] += xv.z * cv.y;
        acc[2][2] += xv.z * cv.z; acc[2][3] += xv.z * cv.w;
        acc[3][0] += xv.w * cv.x; acc[3][1] += xv.w * cv.y;
        acc[3][2] += xv.w * cv.z; acc[3][3] += xv.w * cv.w;
    }

    float2 c0v = cni[tx * 4 + 0], c1v = cni[tx * 4 + 1];
    float2 c2v = cni[tx * 4 + 2], c3v = cni[tx * 4 + 3];
    #pragma unroll
    for (int i = 0; i < 4; ++i) {
        float xb = xn[ty * 4 + i];
        float4 ev;
        ev.x = fmaxf(xb + c0v.x - 2.f * acc[i][0], 0.f) * c0v.y;
        ev.y = fmaxf(xb + c1v.x - 2.f * acc[i][1], 0.f) * c1v.y;
        ev.z = fmaxf(xb + c2v.x - 2.f * acc[i][2], 0.f) * c2v.y;
        ev.w = fmaxf(xb + c3v.x - 2.f * acc[i][3], 0.f) * c3v.y;
        *(float4*)&E[(size_t)(b0 + ty * 4 + i) * NCEN + d0 + tx * 4] = ev;
    }
}

// ---------------------------------------------------------------------------
// Pass B: per (b,seg) row of E: min, ladder threshold, compact to (idx,val),
// HIST counts. One wave per row; all reductions via 64-wide shuffles.
// ---------------------------------------------------------------------------
__global__ __launch_bounds__(256) void rowselect(
    const float* __restrict__ E,
    int* __restrict__ CNT, int* __restrict__ IDX, float* __restrict__ VAL,
    int* __restrict__ HIST)
{
    const int tid = threadIdx.x;
    const int lane = tid & 63;
    const int row = blockIdx.x * 4 + (tid >> 6);   // row = b*4 + seg
    const int b = row >> 2, seg = row & 3;
    const float* er = &E[(size_t)b * NCEN + seg * SEG];

    float4 ea = *(const float4*)&er[lane * 8];
    float4 eb = *(const float4*)&er[lane * 8 + 4];
    float e[8] = {ea.x, ea.y, ea.z, ea.w, eb.x, eb.y, eb.z, eb.w};

    float m = e[0];
    #pragma unroll
    for (int q = 1; q < 8; ++q) m = fminf(m, e[q]);
    m = wave_min_f(m);

    int c0 = 0;
    #pragma unroll
    for (int q = 0; q < 8; ++q) c0 += (e[q] <= m + 16.5f) ? 1 : 0;
    c0 = wave_sum_i(c0);

    float Tp = 16.5f;
    if (c0 > CAP) {
        const float rungs[5] = {12.f, 9.f, 6.f, 4.f, 2.f};
        Tp = 0.75f;
        for (int rI = 0; rI < 5; ++rI) {
            int cc = 0;
            #pragma unroll
            for (int q = 0; q < 8; ++q) cc += (e[q] <= m + rungs[rI]) ? 1 : 0;
            cc = wave_sum_i(cc);
            if (cc <= CAP) { Tp = rungs[rI]; break; }
        }
    }
    const float thr = m + Tp;

    int loc = 0;
    #pragma unroll
    for (int q = 0; q < 8; ++q) loc += (e[q] <= thr) ? 1 : 0;
    int incl = loc, t;
    t = __shfl_up(incl, 1);  if (lane >= 1)  incl += t;
    t = __shfl_up(incl, 2);  if (lane >= 2)  incl += t;
    t = __shfl_up(incl, 4);  if (lane >= 4)  incl += t;
    t = __shfl_up(incl, 8);  if (lane >= 8)  incl += t;
    t = __shfl_up(incl, 16); if (lane >= 16) incl += t;
    t = __shfl_up(incl, 32); if (lane >= 32) incl += t;
    const int excl = incl - loc;
    const int total = __shfl(incl, 63);

    const int base = row * CAP;
    int slot = excl;
    #pragma unroll
    for (int q = 0; q < 8; ++q) {
        bool pass = (e[q] <= thr);
        if (pass && slot < CAP) {
            IDX[base + slot] = lane * 8 + q;          // seg-local d
            VAL[base + slot] = expf(-e[q]);
            atomicAdd(&HIST[seg * SEG + lane * 8 + q], 1);
        }
        if (pass) slot++;
    }
    if (lane == 0) CNT[row] = total < CAP ? total : CAP;
}

// ---------------------------------------------------------------------------
// Scan: per segment, exclusive prefix over 512 bins (one wave per segment).
// ---------------------------------------------------------------------------
__global__ __launch_bounds__(64) void scan_kernel(
    const int* __restrict__ HIST, int* __restrict__ OFFS, int* __restrict__ CUR)
{
    const int seg = blockIdx.x, lane = threadIdx.x;
    int h[8], s = 0;
    #pragma unroll
    for (int i = 0; i < 8; ++i) { h[i] = HIST[seg * SEG + lane * 8 + i]; s += h[i]; }
    int incl = s, t;
    t = __shfl_up(incl, 1);  if (lane >= 1)  incl += t;
    t = __shfl_up(incl, 2);  if (lane >= 2)  incl += t;
    t = __shfl_up(incl, 4);  if (lane >= 4)  incl += t;
    t = __shfl_up(incl, 8);  if (lane >= 8)  incl += t;
    t = __shfl_up(incl, 16); if (lane >= 16) incl += t;
    t = __shfl_up(incl, 32); if (lane >= 32) incl += t;
    int run = incl - s;
    #pragma unroll
    for (int i = 0; i < 8; ++i) {
        OFFS[seg * SEG + lane * 8 + i] = run;
        CUR[seg * SEG + lane * 8 + i] = run;
        run += h[i];
    }
}

// ---------------------------------------------------------------------------
// Scatter: forward lists -> per-d inverted lists (segs 1..3), recording each
// forward entry's inverted (seg-local) position in POS.
// ---------------------------------------------------------------------------
__global__ __launch_bounds__(256) void scatter_kernel(
    const int* __restrict__ CNT, const int* __restrict__ IDX,
    const float* __restrict__ VAL, int* __restrict__ CUR,
    int* __restrict__ BL, float* __restrict__ PV, int* __restrict__ POS)
{
    const int tid = threadIdx.x;
    const int b = blockIdx.x * 4 + (tid >> 6);
    const int seg = blockIdx.y + 1;
    const int lane = tid & 63;
    const int cnt = CNT[b * 4 + seg];
    if (lane < cnt) {
        const int base = (b * 4 + seg) * CAP;
        int d = IDX[base + lane];
        float v = VAL[base + lane];
        int pos = atomicAdd(&CUR[seg * SEG + d], 1);
        BL[(size_t)seg * NBCAP + pos] = b;
        PV[(size_t)seg * NBCAP + pos] = v;
        POS[base + lane] = pos;
    }
}

// ---------------------------------------------------------------------------
// R0[b,i] = sum_t val_t * G0[d_t,i]. One wave per b (4 waves/block).
// ---------------------------------------------------------------------------
__global__ __launch_bounds__(256) void r0_sparse(
    const float* __restrict__ G0,
    const int* __restrict__ CNT, const int* __restrict__ IDX,
    const float* __restrict__ VAL, float* __restrict__ R0v)
{
    const int tid = threadIdx.x;
    const int b = blockIdx.x * 4 + (tid >> 6);
    const int lane = tid & 63;
    const int tg = lane >> 4, iq = lane & 15;
    const int cnt = CNT[b * 4];
    const int base = b * 4 * CAP;
    float4 acc = make_float4(0.f, 0.f, 0.f, 0.f);
    for (int t = tg; t < cnt; t += 4) {
        int d = IDX[base + t];
        float v = VAL[base + t];
        float4 g = *(const float4*)&G0[(size_t)d * RK + iq * 4];
        acc.x += v * g.x; acc.y += v * g.y; acc.z += v * g.z; acc.w += v * g.w;
    }
    acc.x += __shfl_xor(acc.x, 16); acc.y += __shfl_xor(acc.y, 16);
    acc.z += __shfl_xor(acc.z, 16); acc.w += __shfl_xor(acc.w, 16);
    acc.x += __shfl_xor(acc.x, 32); acc.y += __shfl_xor(acc.y, 32);
    acc.z += __shfl_xor(acc.z, 32); acc.w += __shfl_xor(acc.w, 32);
    if (tg == 0) *(float4*)&R0v[(size_t)b * RK + iq * 4] = acc;
}

// ---------------------------------------------------------------------------
// Inverted stage (no atomics), 2 entries per thread: block = (d, part).
// Gd = G[:,d,:] in LDS once; per entry CONTRIB[pos][j] = phi * (Gd^T tin[b]).
// ---------------------------------------------------------------------------
template <int NOUT>
__global__ __launch_bounds__(256) void inv_stage(
    const float* __restrict__ TIN, const float* __restrict__ G,
    const int* __restrict__ HISTs, const int* __restrict__ OFFSs,
    const int* __restrict__ BLs, const float* __restrict__ PVs,
    float* __restrict__ CONTRIB)
{
    constexpr int JL = NOUT / 4;             // j-quad lanes (16 / 8)
    constexpr int CH = 512 / JL;             // entries per chunk (32 / 64)
    __shared__ float gd[64 * NOUT];
    __shared__ float tins[CH * 68];

    const int tid = threadIdx.x;
    const int d = blockIdx.x, part = blockIdx.y;
    const int len = HISTs[d];
    if (len == 0) return;
    const int off0 = OFFSs[d];

    #pragma unroll
    for (int p = 0; p < (64 * NOUT / 4) / 256; ++p) {
        int f = p * 256 + tid;
        int k = f / (NOUT / 4), jj = f % (NOUT / 4);
        *(float4*)&gd[k * NOUT + jj * 4] =
            *(const float4*)&G[((size_t)k * SEG + d) * NOUT + jj * 4];
    }

    const int egp = tid / JL, jq = tid % JL;
    const int e0 = egp * 2, e1 = egp * 2 + 1;

    for (int c = part; c * CH < len; c += 2) {
        __syncthreads();   // gd ready (1st iter); prev chunk readers done
        #pragma unroll
        for (int p = 0; p < (CH * 16) / 256; ++p) {
            int f = p * 256 + tid;
            int en = f >> 4, c4 = (f & 15) * 4;
            int eidx = c * CH + en;
            int brow = (eidx < len) ? BLs[off0 + eidx] : 0;
            *(float4*)&tins[en * 68 + c4] =
                *(const float4*)&TIN[(size_t)brow * RK + c4];
        }
        __syncthreads();

        float4 a0 = make_float4(0.f, 0.f, 0.f, 0.f);
        float4 a1 = make_float4(0.f, 0.f, 0.f, 0.f);
        #pragma unroll 8
        for (int k = 0; k < 64; ++k) {
            float t0 = tins[e0 * 68 + k];
            float t1 = tins[e1 * 68 + k];
            float4 gv = *(const float4*)&gd[k * NOUT + jq * 4];
            a0.x += t0 * gv.x; a0.y += t0 * gv.y;
            a0.z += t0 * gv.z; a0.w += t0 * gv.w;
            a1.x += t1 * gv.x; a1.y += t1 * gv.y;
            a1.z += t1 * gv.z; a1.w += t1 * gv.w;
        }
        const int i0 = c * CH + e0, i1 = c * CH + e1;
        if (i0 < len) {
            float ph = PVs[off0 + i0];
            float4 v = make_float4(ph * a0.x, ph * a0.y, ph * a0.z, ph * a0.w);
            *(float4*)&CONTRIB[(size_t)(off0 + i0) * NOUT + jq * 4] = v;
        }
        if (i1 < len) {
            float ph = PVs[off0 + i1];
            float4 v = make_float4(ph * a1.x, ph * a1.y, ph * a1.z, ph * a1.w);
            *(float4*)&CONTRIB[(size_t)(off0 + i1) * NOUT + jq * 4] = v;
        }
    }
}

// ---------------------------------------------------------------------------
// Gather (owner-writes): tout[b,j] = sum_{t<cnt} CONTRIB[POS[b,t]][j].
// ---------------------------------------------------------------------------
template <int NOUT>
__global__ __launch_bounds__(256) void gather_kernel(
    const int* __restrict__ CNT, const int* __restrict__ POS,
    const float* __restrict__ CONTRIB, float* __restrict__ TOUT, int seg)
{
    constexpr int JL = NOUT / 4;
    constexpr int TG = 64 / JL;
    const int tid = threadIdx.x;
    const int b = blockIdx.x * 4 + (tid >> 6);
    const int lane = tid & 63;
    const int tg = lane / JL, iq = lane % JL;
    const int cnt = CNT[b * 4 + seg];
    const int base = (b * 4 + seg) * CAP;
    float4 acc = make_float4(0.f, 0.f, 0.f, 0.f);
    for (int t = tg; t < cnt; t += TG) {
        int pos = POS[base + t];
        float4 v = *(const float4*)&CONTRIB[(size_t)pos * NOUT + iq * 4];
        acc.x += v.x; acc.y += v.y; acc.z += v.z; acc.w += v.w;
    }
    #pragma unroll
    for (int off = JL; off < 64; off <<= 1) {
        acc.x += __shfl_xor(acc.x, off); acc.y += __shfl_xor(acc.y, off);
        acc.z += __shfl_xor(acc.z, off); acc.w += __shfl_xor(acc.w, off);
    }
    if (tg == 0) *(float4*)&TOUT[(size_t)b * NOUT + iq * 4] = acc;
}

// ---------------------------------------------------------------------------
extern "C" void kernel_launch(void* const* d_in, const int* in_sizes, int n_in,
                              void* d_out, int out_size, void* d_ws, size_t ws_size,
                              hipStream_t stream)
{
    const float* X  = (const float*)d_in[0];
    const float* C  = (const float*)d_in[1];
    const float* LS = (const float*)d_in[2];
    const float* G0 = (const float*)d_in[3];
    const float* G1 = (const float*)d_in[4];
    const float* G2 = (const float*)d_in[5];
    const float* G3 = (const float*)d_in[6];
    float* out = (float*)d_out;

    // LAYOUT FIX (R5 crash root-cause): actual per-seg inverted-list totals
    // are ~200K entries (avg ~50/row, NOT ~15), so CONTRIB's true extent is
    // up to 67 MB (worst case NBCAP*NOUT*4). R5 overlaid it on E's 33.5 MB
    // region and it overran into CNT/IDX/POS -> garbage POS -> page fault.
    // Now E (33.5 MB, dead after rowselect) and CONTRIB (written only later
    // by inv_stage) SHARE one full-size 67 MB region; metadata follows.
    // Total footprint = 91,316,224 B, byte-identical to R4's proven layout.
    char* ws = (char*)d_ws;
    float* E       = (float*)ws;
    float* CONTRIB = (float*)ws;
    size_t o = (size_t)NBCAP * RK * 4;                             // 67 MB
    int*   CNT  = (int*)(ws + o);   o += (size_t)NB * 4 * 4;       // 64 KB
    int*   IDX  = (int*)(ws + o);   o += (size_t)NB * 4 * CAP * 4; // 4 MB
    float* VAL  = (float*)(ws + o); o += (size_t)NB * 4 * CAP * 4; // 4 MB
    int*   POS  = (int*)(ws + o);   o += (size_t)NB * 4 * CAP * 4; // 4 MB
    int*   HIST = (int*)(ws + o);   o += 4 * SEG * 4;
    int*   OFFS = (int*)(ws + o);   o += 4 * SEG * 4;
    int*   CUR  = (int*)(ws + o);   o += 4 * SEG * 4;
    int*   BL   = (int*)(ws + o);   o += (size_t)4 * NBCAP * 4;    // 4 MB
    float* PV   = (float*)(ws + o); o += (size_t)4 * NBCAP * 4;    // 4 MB
    float* R0v  = (float*)(ws + o); o += (size_t)NB * RK * 4;      // 1 MB
    float* t1   = (float*)(ws + o); o += (size_t)NB * RK * 4;      // 1 MB
    float* t2   = (float*)(ws + o); o += (size_t)NB * RK * 4;      // 1 MB

    e_gemm<<<dim3(NCEN / 64, NB / 64), 256, 0, stream>>>(X, C, LS, E, HIST);
    rowselect<<<(NB * 4) / 4, 256, 0, stream>>>(E, CNT, IDX, VAL, HIST);
    scan_kernel<<<4, 64, 0, stream>>>(HIST, OFFS, CUR);
    scatter_kernel<<<dim3(NB / 4, 3), 256, 0, stream>>>(CNT, IDX, VAL, CUR, BL, PV, POS);
    r0_sparse<<<NB / 4, 256, 0, stream>>>(G0, CNT, IDX, VAL, R0v);

    inv_stage<64><<<dim3(SEG, 2), 256, 0, stream>>>(
        R0v, G1, HIST + SEG, OFFS + SEG, BL + (size_t)NBCAP, PV + (size_t)NBCAP, CONTRIB);
    gather_kernel<64><<<NB / 4, 256, 0, stream>>>(CNT, POS, CONTRIB, t1, 1);

    inv_stage<64><<<dim3(SEG, 2), 256, 0, stream>>>(
        t1, G2, HIST + 2 * SEG, OFFS + 2 * SEG, BL + (size_t)2 * NBCAP, PV + (size_t)2 * NBCAP, CONTRIB);
    gather_kernel<64><<<NB / 4, 256, 0, stream>>>(CNT, POS, CONTRIB, t2, 2);

    inv_stage<32><<<dim3(SEG, 2), 256, 0, stream>>>(
        t2, G3, HIST + 3 * SEG, OFFS + 3 * SEG, BL + (size_t)3 * NBCAP, PV + (size_t)3 * NBCAP, CONTRIB);
    gather_kernel<32><<<NB / 4, 256, 0, stream>>>(CNT, POS, CONTRIB, out, 3);
}

// Round 7
// 430.743 us; speedup vs baseline: 2.0730x; 1.4885x over previous
//
#include <hip/hip_runtime.h>
#include <math.h>

// Problem constants
#define NB    4096   // batch
#define NCEN  2048   // centres
#define DX    32     // feature dim
#define SEG   512    // centres per segment
#define RK    64     // TT rank
#define CAP   64     // max kept centres per (b, segment)
#define NBCAP (NB * CAP)
#define NCH   64     // b-chunks of 64 rows each (for two-level scatter scan)

static __device__ __forceinline__ int wave_sum_i(int v) {
    v += __shfl_xor(v, 1);  v += __shfl_xor(v, 2);  v += __shfl_xor(v, 4);
    v += __shfl_xor(v, 8);  v += __shfl_xor(v, 16); v += __shfl_xor(v, 32);
    return v;
}
static __device__ __forceinline__ float wave_min_f(float v) {
    v = fminf(v, __shfl_xor(v, 1));  v = fminf(v, __shfl_xor(v, 2));
    v = fminf(v, __shfl_xor(v, 4));  v = fminf(v, __shfl_xor(v, 8));
    v = fminf(v, __shfl_xor(v, 16)); v = fminf(v, __shfl_xor(v, 32));
    return v;
}

// ---------------------------------------------------------------------------
// Pass A: E[b,d] = max(||x||^2+||c||^2-2 x.c, 0) * exp(-2 ls_d)
// Register-tiled GEMM: 64x64 tile, 256 threads, 4bx4d per thread, K=32.
// ---------------------------------------------------------------------------
__global__ __launch_bounds__(256) void e_gemm(
    const float* __restrict__ X, const float* __restrict__ C,
    const float* __restrict__ LS, float* __restrict__ E)
{
    __shared__ float XT[32 * 68];    // [k][b], stride 68
    __shared__ float CT[32 * 68];    // [k][d]
    __shared__ float xn[64];
    __shared__ float2 cni[64];       // (||c||^2, exp(-2 ls))

    const int tid = threadIdx.x;
    const int d0 = blockIdx.x * 64, b0 = blockIdx.y * 64;

    #pragma unroll
    for (int p = 0; p < 2; ++p) {
        int f = p * 256 + tid;               // 0..511
        int r = f >> 3, c4 = (f & 7) * 4;
        float4 xv = *(const float4*)&X[(size_t)(b0 + r) * DX + c4];
        XT[(c4 + 0) * 68 + r] = xv.x; XT[(c4 + 1) * 68 + r] = xv.y;
        XT[(c4 + 2) * 68 + r] = xv.z; XT[(c4 + 3) * 68 + r] = xv.w;
        float4 cv = *(const float4*)&C[(size_t)(d0 + r) * DX + c4];
        CT[(c4 + 0) * 68 + r] = cv.x; CT[(c4 + 1) * 68 + r] = cv.y;
        CT[(c4 + 2) * 68 + r] = cv.z; CT[(c4 + 3) * 68 + r] = cv.w;
    }
    __syncthreads();

    if (tid < 64) {
        float s = 0.f;
        for (int k = 0; k < 32; ++k) { float v = XT[k * 68 + tid]; s += v * v; }
        xn[tid] = s;
    } else if (tid < 128) {
        int d = tid - 64;
        float s = 0.f;
        for (int k = 0; k < 32; ++k) { float v = CT[k * 68 + d]; s += v * v; }
        cni[d] = make_float2(s, expf(-2.f * LS[d0 + d]));
    }
    __syncthreads();

    const int ty = tid >> 4, tx = tid & 15;
    float acc[4][4] = {};
    #pragma unroll 8
    for (int k = 0; k < 32; ++k) {
        float4 xv = *(const float4*)&XT[k * 68 + ty * 4];
        float4 cv = *(const float4*)&CT[k * 68 + tx * 4];
        acc[0][0] += xv.x * cv.x; acc[0][1] += xv.x * cv.y;
        acc[0][2] += xv.x * cv.z; acc[0][3] += xv.x * cv.w;
        acc[1][0] += xv.y * cv.x; acc[1][1] += xv.y * cv.y;
        acc[1][2] += xv.y * cv.z; acc[1][3] += xv.y * cv.w;
        acc[2][0] += xv.z * cv.x; acc[2][1] += xv.z * cv.y;
        acc[2][2] += xv.z * cv.z; acc[2][3] += xv.z * cv.w;
        acc[3][0] += xv.w * cv.x; acc[3][1] += xv.w * cv.y;
        acc[3][2] += xv.w * cv.z; acc[3][3] += xv.w * cv.w;
    }

    float2 c0v = cni[tx * 4 + 0], c1v = cni[tx * 4 + 1];
    float2 c2v = cni[tx * 4 + 2], c3v = cni[tx * 4 + 3];
    #pragma unroll
    for (int i = 0; i < 4; ++i) {
        float xb = xn[ty * 4 + i];
        float4 ev;
        ev.x = fmaxf(xb + c0v.x - 2.f * acc[i][0], 0.f) * c0v.y;
        ev.y = fmaxf(xb + c1v.x - 2.f * acc[i][1], 0.f) * c1v.y;
        ev.z = fmaxf(xb + c2v.x - 2.f * acc[i][2], 0.f) * c2v.y;
        ev.w = fmaxf(xb + c3v.x - 2.f * acc[i][3], 0.f) * c3v.y;
        *(float4*)&E[(size_t)(b0 + ty * 4 + i) * NCEN + d0 + tx * 4] = ev;
    }
}

// ---------------------------------------------------------------------------
// Pass B: per (b,seg) row of E: min, ladder threshold, compact to (idx,val).
// Histograms into per-chunk bins HIST2[seg][b>>6][d] (fire-and-forget
// atomics, ~6 hits/bin -> no serialization).
// ---------------------------------------------------------------------------
__global__ __launch_bounds__(256) void rowselect(
    const float* __restrict__ E,
    int* __restrict__ CNT, int* __restrict__ IDX, float* __restrict__ VAL,
    int* __restrict__ HIST2)
{
    const int tid = threadIdx.x;
    const int lane = tid & 63;
    const int row = blockIdx.x * 4 + (tid >> 6);   // row = b*4 + seg
    const int b = row >> 2, seg = row & 3;
    const float* er = &E[(size_t)b * NCEN + seg * SEG];

    float4 ea = *(const float4*)&er[lane * 8];
    float4 eb = *(const float4*)&er[lane * 8 + 4];
    float e[8] = {ea.x, ea.y, ea.z, ea.w, eb.x, eb.y, eb.z, eb.w};

    float m = e[0];
    #pragma unroll
    for (int q = 1; q < 8; ++q) m = fminf(m, e[q]);
    m = wave_min_f(m);

    int c0 = 0;
    #pragma unroll
    for (int q = 0; q < 8; ++q) c0 += (e[q] <= m + 16.5f) ? 1 : 0;
    c0 = wave_sum_i(c0);

    float Tp = 16.5f;
    if (c0 > CAP) {
        const float rungs[5] = {12.f, 9.f, 6.f, 4.f, 2.f};
        Tp = 0.75f;
        for (int rI = 0; rI < 5; ++rI) {
            int cc = 0;
            #pragma unroll
            for (int q = 0; q < 8; ++q) cc += (e[q] <= m + rungs[rI]) ? 1 : 0;
            cc = wave_sum_i(cc);
            if (cc <= CAP) { Tp = rungs[rI]; break; }
        }
    }
    const float thr = m + Tp;

    int loc = 0;
    #pragma unroll
    for (int q = 0; q < 8; ++q) loc += (e[q] <= thr) ? 1 : 0;
    int incl = loc, t;
    t = __shfl_up(incl, 1);  if (lane >= 1)  incl += t;
    t = __shfl_up(incl, 2);  if (lane >= 2)  incl += t;
    t = __shfl_up(incl, 4);  if (lane >= 4)  incl += t;
    t = __shfl_up(incl, 8);  if (lane >= 8)  incl += t;
    t = __shfl_up(incl, 16); if (lane >= 16) incl += t;
    t = __shfl_up(incl, 32); if (lane >= 32) incl += t;
    const int excl = incl - loc;
    const int total = __shfl(incl, 63);

    const int base = row * CAP;
    int* h2 = &HIST2[(seg * NCH + (b >> 6)) * SEG];
    int slot = excl;
    #pragma unroll
    for (int q = 0; q < 8; ++q) {
        bool pass = (e[q] <= thr);
        if (pass && slot < CAP) {
            IDX[base + slot] = lane * 8 + q;          // seg-local d
            VAL[base + slot] = expf(-e[q]);
            atomicAdd(&h2[lane * 8 + q], 1);          // fire-and-forget
        }
        if (pass) slot++;
    }
    if (lane == 0) CNT[row] = total < CAP ? total : CAP;
}

// ---------------------------------------------------------------------------
// scan2: per segment, totals + global exclusive scan over 512 d-bins +
// per-chunk exclusive offsets CHOFF[seg][chunk][d]. Block per seg.
// ---------------------------------------------------------------------------
__global__ __launch_bounds__(256) void scan2_kernel(
    const int* __restrict__ HIST2, int* __restrict__ OFFS,
    int* __restrict__ LEN, int* __restrict__ CHOFF)
{
    __shared__ int wsum[4];
    const int seg = blockIdx.x;
    const int tid = threadIdx.x;
    const int lane = tid & 63, wave = tid >> 6;
    const int d0 = tid * 2, d1 = tid * 2 + 1;

    int tot0 = 0, tot1 = 0;
    for (int c = 0; c < NCH; ++c) {
        tot0 += HIST2[(seg * NCH + c) * SEG + d0];
        tot1 += HIST2[(seg * NCH + c) * SEG + d1];
    }
    int s = tot0 + tot1;
    int incl = s, t;
    t = __shfl_up(incl, 1);  if (lane >= 1)  incl += t;
    t = __shfl_up(incl, 2);  if (lane >= 2)  incl += t;
    t = __shfl_up(incl, 4);  if (lane >= 4)  incl += t;
    t = __shfl_up(incl, 8);  if (lane >= 8)  incl += t;
    t = __shfl_up(incl, 16); if (lane >= 16) incl += t;
    t = __shfl_up(incl, 32); if (lane >= 32) incl += t;
    if (lane == 63) wsum[wave] = incl;
    __syncthreads();
    int woff = 0;
    #pragma unroll
    for (int w = 0; w < 4; ++w) if (w < wave) woff += wsum[w];
    const int excl = woff + incl - s;

    OFFS[seg * SEG + d0] = excl;
    OFFS[seg * SEG + d1] = excl + tot0;
    LEN[seg * SEG + d0] = tot0;
    LEN[seg * SEG + d1] = tot1;

    int run0 = excl, run1 = excl + tot0;
    for (int c = 0; c < NCH; ++c) {
        int i0 = (seg * NCH + c) * SEG + d0;
        CHOFF[i0] = run0;     run0 += HIST2[i0];
        CHOFF[i0 + 1] = run1; run1 += HIST2[i0 + 1];
    }
}

// ---------------------------------------------------------------------------
// Scatter (LDS atomics only): block = (chunk of 64 b's, seg in 1..3).
// cur[512] seeded from CHOFF; collision-free pos; writes BL/PV/POS.
// ---------------------------------------------------------------------------
__global__ __launch_bounds__(256) void scatter_kernel(
    const int* __restrict__ CNT, const int* __restrict__ IDX,
    const float* __restrict__ VAL, const int* __restrict__ CHOFF,
    int* __restrict__ BL, float* __restrict__ PV, int* __restrict__ POS)
{
    __shared__ int cur[SEG];
    const int tid = threadIdx.x;
    const int chunk = blockIdx.x;
    const int seg = blockIdx.y + 1;
    cur[tid] = CHOFF[(seg * NCH + chunk) * SEG + tid];
    cur[tid + 256] = CHOFF[(seg * NCH + chunk) * SEG + tid + 256];
    __syncthreads();

    const int wave = tid >> 6, lane = tid & 63;
    #pragma unroll 4
    for (int i = 0; i < 16; ++i) {
        const int b = chunk * 64 + wave * 16 + i;
        const int cnt = CNT[b * 4 + seg];
        if (lane < cnt) {
            const int base = (b * 4 + seg) * CAP;
            int d = IDX[base + lane];
            float v = VAL[base + lane];
            int pos = atomicAdd(&cur[d], 1);          // LDS atomic
            BL[(size_t)(seg - 1) * NBCAP + pos] = b;
            PV[(size_t)(seg - 1) * NBCAP + pos] = v;
            POS[base + lane] = pos;
        }
    }
}

// ---------------------------------------------------------------------------
// R0[b,i] = sum_t val_t * G0[d_t,i]. One wave per b (4 waves/block).
// ---------------------------------------------------------------------------
__global__ __launch_bounds__(256) void r0_sparse(
    const float* __restrict__ G0,
    const int* __restrict__ CNT, const int* __restrict__ IDX,
    const float* __restrict__ VAL, float* __restrict__ R0v)
{
    const int tid = threadIdx.x;
    const int b = blockIdx.x * 4 + (tid >> 6);
    const int lane = tid & 63;
    const int tg = lane >> 4, iq = lane & 15;
    const int cnt = CNT[b * 4];
    const int base = b * 4 * CAP;
    float4 acc = make_float4(0.f, 0.f, 0.f, 0.f);
    for (int t = tg; t < cnt; t += 4) {
        int d = IDX[base + t];
        float v = VAL[base + t];
        float4 g = *(const float4*)&G0[(size_t)d * RK + iq * 4];
        acc.x += v * g.x; acc.y += v * g.y; acc.z += v * g.z; acc.w += v * g.w;
    }
    acc.x += __shfl_xor(acc.x, 16); acc.y += __shfl_xor(acc.y, 16);
    acc.z += __shfl_xor(acc.z, 16); acc.w += __shfl_xor(acc.w, 16);
    acc.x += __shfl_xor(acc.x, 32); acc.y += __shfl_xor(acc.y, 32);
    acc.z += __shfl_xor(acc.z, 32); acc.w += __shfl_xor(acc.w, 32);
    if (tg == 0) *(float4*)&R0v[(size_t)b * RK + iq * 4] = acc;
}

// ---------------------------------------------------------------------------
// Inverted stage (no atomics), EPT entries per thread: block = (d, part).
// Gd = G[:,d,:] in LDS once; per entry CONTRIB[pos][j] = phi * (Gd^T tin[b]).
// ---------------------------------------------------------------------------
template <int NOUT, int EPT>
__global__ __launch_bounds__(256) void inv_stage(
    const float* __restrict__ TIN, const float* __restrict__ G,
    const int* __restrict__ LENs, const int* __restrict__ OFFSs,
    const int* __restrict__ BLs, const float* __restrict__ PVs,
    float* __restrict__ CONTRIB)
{
    constexpr int JL = NOUT / 4;             // j-quad lanes (16 / 8)
    constexpr int NG = 256 / JL;             // entry groups (16 / 32)
    constexpr int CH = NG * EPT;             // entries per chunk
    __shared__ float gd[64 * NOUT];
    __shared__ float tins[CH * 68];

    const int tid = threadIdx.x;
    const int d = blockIdx.x, part = blockIdx.y;
    const int len = LENs[d];
    if (len == 0) return;
    const int off0 = OFFSs[d];

    #pragma unroll
    for (int p = 0; p < (64 * NOUT / 4) / 256; ++p) {
        int f = p * 256 + tid;
        int k = f / (NOUT / 4), jj = f % (NOUT / 4);
        *(float4*)&gd[k * NOUT + jj * 4] =
            *(const float4*)&G[((size_t)k * SEG + d) * NOUT + jj * 4];
    }

    const int egp = tid / JL, jq = tid % JL;

    for (int c = part; c * CH < len; c += 2) {
        __syncthreads();   // gd ready (1st iter); prev chunk readers done
        #pragma unroll
        for (int p = 0; p < (CH * 16) / 256; ++p) {
            int f = p * 256 + tid;
            int en = f >> 4, c4 = (f & 15) * 4;
            int eidx = c * CH + en;
            int brow = (eidx < len) ? BLs[off0 + eidx] : 0;
            *(float4*)&tins[en * 68 + c4] =
                *(const float4*)&TIN[(size_t)brow * RK + c4];
        }
        __syncthreads();

        float4 a[EPT];
        #pragma unroll
        for (int q = 0; q < EPT; ++q) a[q] = make_float4(0.f, 0.f, 0.f, 0.f);

        #pragma unroll 4
        for (int k = 0; k < 64; ++k) {
            float4 gv = *(const float4*)&gd[k * NOUT + jq * 4];
            #pragma unroll
            for (int q = 0; q < EPT; ++q) {
                float tv = tins[(egp * EPT + q) * 68 + k];
                a[q].x += tv * gv.x; a[q].y += tv * gv.y;
                a[q].z += tv * gv.z; a[q].w += tv * gv.w;
            }
        }
        #pragma unroll
        for (int q = 0; q < EPT; ++q) {
            const int ie = c * CH + egp * EPT + q;
            if (ie < len) {
                float ph = PVs[off0 + ie];
                float4 v = make_float4(ph * a[q].x, ph * a[q].y,
                                       ph * a[q].z, ph * a[q].w);
                *(float4*)&CONTRIB[(size_t)(off0 + ie) * NOUT + jq * 4] = v;
            }
        }
    }
}

// ---------------------------------------------------------------------------
// Gather (owner-writes): tout[b,j] = sum_{t<cnt} CONTRIB[POS[b,t]][j].
// ---------------------------------------------------------------------------
template <int NOUT>
__global__ __launch_bounds__(256) void gather_kernel(
    const int* __restrict__ CNT, const int* __restrict__ POS,
    const float* __restrict__ CONTRIB, float* __restrict__ TOUT, int seg)
{
    constexpr int JL = NOUT / 4;
    constexpr int TG = 64 / JL;
    const int tid = threadIdx.x;
    const int b = blockIdx.x * 4 + (tid >> 6);
    const int lane = tid & 63;
    const int tg = lane / JL, iq = lane % JL;
    const int cnt = CNT[b * 4 + seg];
    const int base = (b * 4 + seg) * CAP;
    float4 acc = make_float4(0.f, 0.f, 0.f, 0.f);
    for (int t = tg; t < cnt; t += TG) {
        int pos = POS[base + t];
        float4 v = *(const float4*)&CONTRIB[(size_t)pos * NOUT + iq * 4];
        acc.x += v.x; acc.y += v.y; acc.z += v.z; acc.w += v.w;
    }
    #pragma unroll
    for (int off = JL; off < 64; off <<= 1) {
        acc.x += __shfl_xor(acc.x, off); acc.y += __shfl_xor(acc.y, off);
        acc.z += __shfl_xor(acc.z, off); acc.w += __shfl_xor(acc.w, off);
    }
    if (tg == 0) *(float4*)&TOUT[(size_t)b * NOUT + iq * 4] = acc;
}

// ---------------------------------------------------------------------------
extern "C" void kernel_launch(void* const* d_in, const int* in_sizes, int n_in,
                              void* d_out, int out_size, void* d_ws, size_t ws_size,
                              hipStream_t stream)
{
    const float* X  = (const float*)d_in[0];
    const float* C  = (const float*)d_in[1];
    const float* LS = (const float*)d_in[2];
    const float* G0 = (const float*)d_in[3];
    const float* G1 = (const float*)d_in[4];
    const float* G2 = (const float*)d_in[5];
    const float* G3 = (const float*)d_in[6];
    float* out = (float*)d_out;

    // E (33.5 MB, dead after rowselect) and CONTRIB (<=67 MB, written only by
    // inv_stage) share one full-size region. Total footprint 90.3 MB
    // (< R4's proven 91.3 MB).
    char* ws = (char*)d_ws;
    float* E       = (float*)ws;
    float* CONTRIB = (float*)ws;
    size_t o = (size_t)NBCAP * RK * 4;                              // 67 MB
    int*   CNT   = (int*)(ws + o);   o += (size_t)NB * 4 * 4;       // 64 KB
    int*   IDX   = (int*)(ws + o);   o += (size_t)NB * 4 * CAP * 4; // 4 MB
    float* VAL   = (float*)(ws + o); o += (size_t)NB * 4 * CAP * 4; // 4 MB
    int*   POS   = (int*)(ws + o);   o += (size_t)NB * 4 * CAP * 4; // 4 MB
    int*   HIST2 = (int*)(ws + o);   o += (size_t)4 * NCH * SEG * 4;// 512 KB
    int*   CHOFF = (int*)(ws + o);   o += (size_t)4 * NCH * SEG * 4;// 512 KB
    int*   OFFS  = (int*)(ws + o);   o += 4 * SEG * 4;              // 8 KB
    int*   LEN   = (int*)(ws + o);   o += 4 * SEG * 4;              // 8 KB
    int*   BL    = (int*)(ws + o);   o += (size_t)3 * NBCAP * 4;    // 3 MB
    float* PV    = (float*)(ws + o); o += (size_t)3 * NBCAP * 4;    // 3 MB
    float* R0v   = (float*)(ws + o); o += (size_t)NB * RK * 4;      // 1 MB
    float* t1    = (float*)(ws + o); o += (size_t)NB * RK * 4;      // 1 MB
    float* t2    = (float*)(ws + o); o += (size_t)NB * RK * 4;      // 1 MB

    hipMemsetAsync(HIST2, 0, (size_t)4 * NCH * SEG * 4, stream);

    e_gemm<<<dim3(NCEN / 64, NB / 64), 256, 0, stream>>>(X, C, LS, E);
    rowselect<<<NB, 256, 0, stream>>>(E, CNT, IDX, VAL, HIST2);
    scan2_kernel<<<4, 256, 0, stream>>>(HIST2, OFFS, LEN, CHOFF);
    scatter_kernel<<<dim3(NCH, 3), 256, 0, stream>>>(CNT, IDX, VAL, CHOFF, BL, PV, POS);
    r0_sparse<<<NB / 4, 256, 0, stream>>>(G0, CNT, IDX, VAL, R0v);

    inv_stage<64, 4><<<dim3(SEG, 2), 256, 0, stream>>>(
        R0v, G1, LEN + SEG, OFFS + SEG, BL, PV, CONTRIB);
    gather_kernel<64><<<NB / 4, 256, 0, stream>>>(CNT, POS, CONTRIB, t1, 1);

    inv_stage<64, 4><<<dim3(SEG, 2), 256, 0, stream>>>(
        t1, G2, LEN + 2 * SEG, OFFS + 2 * SEG, BL + (size_t)NBCAP, PV + (size_t)NBCAP, CONTRIB);
    gather_kernel<64><<<NB / 4, 256, 0, stream>>>(CNT, POS, CONTRIB, t2, 2);

    inv_stage<32, 2><<<dim3(SEG, 2), 256, 0, stream>>>(
        t2, G3, LEN + 3 * SEG, OFFS + 3 * SEG, BL + (size_t)2 * NBCAP, PV + (size_t)2 * NBCAP, CONTRIB);
    gather_kernel<32><<<NB / 4, 256, 0, stream>>>(CNT, POS, CONTRIB, out, 3);
}

// Round 8
// 255.940 us; speedup vs baseline: 3.4888x; 1.6830x over previous
//
#include <hip/hip_runtime.h>
#include <math.h>

// Problem constants
#define NB    4096   // batch
#define NCEN  2048   // centres
#define DX    32     // feature dim
#define SEG   512    // centres per segment
#define RK    64     // TT rank
#define CAP   64     // max kept centres per (b, segment)
#define NBCAP (NB * CAP)
#define NCH   64     // b-chunks of 64 rows each (two-level scatter scan)
#define CHUNK 64     // entries per inv_stage work item
#define QMAX  (NBCAP / CHUNK + SEG)   // 4608 max chunks per segment

static __device__ __forceinline__ int wave_sum_i(int v) {
    v += __shfl_xor(v, 1);  v += __shfl_xor(v, 2);  v += __shfl_xor(v, 4);
    v += __shfl_xor(v, 8);  v += __shfl_xor(v, 16); v += __shfl_xor(v, 32);
    return v;
}
static __device__ __forceinline__ float wave_min_f(float v) {
    v = fminf(v, __shfl_xor(v, 1));  v = fminf(v, __shfl_xor(v, 2));
    v = fminf(v, __shfl_xor(v, 4));  v = fminf(v, __shfl_xor(v, 8));
    v = fminf(v, __shfl_xor(v, 16)); v = fminf(v, __shfl_xor(v, 32));
    return v;
}

// ---------------------------------------------------------------------------
// Pass A: E[b,d] = max(||x||^2+||c||^2-2 x.c, 0) * exp(-2 ls_d)
// ---------------------------------------------------------------------------
__global__ __launch_bounds__(256) void e_gemm(
    const float* __restrict__ X, const float* __restrict__ C,
    const float* __restrict__ LS, float* __restrict__ E)
{
    __shared__ float XT[32 * 68];    // [k][b], stride 68
    __shared__ float CT[32 * 68];    // [k][d]
    __shared__ float xn[64];
    __shared__ float2 cni[64];       // (||c||^2, exp(-2 ls))

    const int tid = threadIdx.x;
    const int d0 = blockIdx.x * 64, b0 = blockIdx.y * 64;

    #pragma unroll
    for (int p = 0; p < 2; ++p) {
        int f = p * 256 + tid;               // 0..511
        int r = f >> 3, c4 = (f & 7) * 4;
        float4 xv = *(const float4*)&X[(size_t)(b0 + r) * DX + c4];
        XT[(c4 + 0) * 68 + r] = xv.x; XT[(c4 + 1) * 68 + r] = xv.y;
        XT[(c4 + 2) * 68 + r] = xv.z; XT[(c4 + 3) * 68 + r] = xv.w;
        float4 cv = *(const float4*)&C[(size_t)(d0 + r) * DX + c4];
        CT[(c4 + 0) * 68 + r] = cv.x; CT[(c4 + 1) * 68 + r] = cv.y;
        CT[(c4 + 2) * 68 + r] = cv.z; CT[(c4 + 3) * 68 + r] = cv.w;
    }
    __syncthreads();

    if (tid < 64) {
        float s = 0.f;
        for (int k = 0; k < 32; ++k) { float v = XT[k * 68 + tid]; s += v * v; }
        xn[tid] = s;
    } else if (tid < 128) {
        int d = tid - 64;
        float s = 0.f;
        for (int k = 0; k < 32; ++k) { float v = CT[k * 68 + d]; s += v * v; }
        cni[d] = make_float2(s, expf(-2.f * LS[d0 + d]));
    }
    __syncthreads();

    const int ty = tid >> 4, tx = tid & 15;
    float acc[4][4] = {};
    #pragma unroll 8
    for (int k = 0; k < 32; ++k) {
        float4 xv = *(const float4*)&XT[k * 68 + ty * 4];
        float4 cv = *(const float4*)&CT[k * 68 + tx * 4];
        acc[0][0] += xv.x * cv.x; acc[0][1] += xv.x * cv.y;
        acc[0][2] += xv.x * cv.z; acc[0][3] += xv.x * cv.w;
        acc[1][0] += xv.y * cv.x; acc[1][1] += xv.y * cv.y;
        acc[1][2] += xv.y * cv.z; acc[1][3] += xv.y * cv.w;
        acc[2][0] += xv.z * cv.x; acc[2][1] += xv.z * cv.y;
        acc[2][2] += xv.z * cv.z; acc[2][3] += xv.z * cv.w;
        acc[3][0] += xv.w * cv.x; acc[3][1] += xv.w * cv.y;
        acc[3][2] += xv.w * cv.z; acc[3][3] += xv.w * cv.w;
    }

    float2 c0v = cni[tx * 4 + 0], c1v = cni[tx * 4 + 1];
    float2 c2v = cni[tx * 4 + 2], c3v = cni[tx * 4 + 3];
    #pragma unroll
    for (int i = 0; i < 4; ++i) {
        float xb = xn[ty * 4 + i];
        float4 ev;
        ev.x = fmaxf(xb + c0v.x - 2.f * acc[i][0], 0.f) * c0v.y;
        ev.y = fmaxf(xb + c1v.x - 2.f * acc[i][1], 0.f) * c1v.y;
        ev.z = fmaxf(xb + c2v.x - 2.f * acc[i][2], 0.f) * c2v.y;
        ev.w = fmaxf(xb + c3v.x - 2.f * acc[i][3], 0.f) * c3v.y;
        *(float4*)&E[(size_t)(b0 + ty * 4 + i) * NCEN + d0 + tx * 4] = ev;
    }
}

// ---------------------------------------------------------------------------
// Pass B: per (b,seg) row: min, ladder threshold, compact; per-chunk hist.
// ---------------------------------------------------------------------------
__global__ __launch_bounds__(256) void rowselect(
    const float* __restrict__ E,
    int* __restrict__ CNT, int* __restrict__ IDX, float* __restrict__ VAL,
    int* __restrict__ HIST2)
{
    const int tid = threadIdx.x;
    const int lane = tid & 63;
    const int row = blockIdx.x * 4 + (tid >> 6);   // row = b*4 + seg
    const int b = row >> 2, seg = row & 3;
    const float* er = &E[(size_t)b * NCEN + seg * SEG];

    float4 ea = *(const float4*)&er[lane * 8];
    float4 eb = *(const float4*)&er[lane * 8 + 4];
    float e[8] = {ea.x, ea.y, ea.z, ea.w, eb.x, eb.y, eb.z, eb.w};

    float m = e[0];
    #pragma unroll
    for (int q = 1; q < 8; ++q) m = fminf(m, e[q]);
    m = wave_min_f(m);

    int c0 = 0;
    #pragma unroll
    for (int q = 0; q < 8; ++q) c0 += (e[q] <= m + 16.5f) ? 1 : 0;
    c0 = wave_sum_i(c0);

    float Tp = 16.5f;
    if (c0 > CAP) {
        const float rungs[5] = {12.f, 9.f, 6.f, 4.f, 2.f};
        Tp = 0.75f;
        for (int rI = 0; rI < 5; ++rI) {
            int cc = 0;
            #pragma unroll
            for (int q = 0; q < 8; ++q) cc += (e[q] <= m + rungs[rI]) ? 1 : 0;
            cc = wave_sum_i(cc);
            if (cc <= CAP) { Tp = rungs[rI]; break; }
        }
    }
    const float thr = m + Tp;

    int loc = 0;
    #pragma unroll
    for (int q = 0; q < 8; ++q) loc += (e[q] <= thr) ? 1 : 0;
    int incl = loc, t;
    t = __shfl_up(incl, 1);  if (lane >= 1)  incl += t;
    t = __shfl_up(incl, 2);  if (lane >= 2)  incl += t;
    t = __shfl_up(incl, 4);  if (lane >= 4)  incl += t;
    t = __shfl_up(incl, 8);  if (lane >= 8)  incl += t;
    t = __shfl_up(incl, 16); if (lane >= 16) incl += t;
    t = __shfl_up(incl, 32); if (lane >= 32) incl += t;
    const int excl = incl - loc;
    const int total = __shfl(incl, 63);

    const int base = row * CAP;
    int* h2 = &HIST2[(seg * NCH + (b >> 6)) * SEG];
    int slot = excl;
    #pragma unroll
    for (int q = 0; q < 8; ++q) {
        bool pass = (e[q] <= thr);
        if (pass && slot < CAP) {
            IDX[base + slot] = lane * 8 + q;          // seg-local d
            VAL[base + slot] = expf(-e[q]);
            atomicAdd(&h2[lane * 8 + q], 1);          // fire-and-forget
        }
        if (pass) slot++;
    }
    if (lane == 0) CNT[row] = total < CAP ? total : CAP;
}

// ---------------------------------------------------------------------------
// scan2: per segment — totals, global exclusive scan, per-chunk offsets,
// AND the flat work queue Q of (d, chunk) descriptors for inv_stage.
// ---------------------------------------------------------------------------
__global__ __launch_bounds__(256) void scan2_kernel(
    const int* __restrict__ HIST2, int* __restrict__ OFFS,
    int* __restrict__ LEN, int* __restrict__ CHOFF,
    int* __restrict__ Q, int* __restrict__ QCNT)
{
    __shared__ int wsum[4], wsum2[4];
    const int seg = blockIdx.x;
    const int tid = threadIdx.x;
    const int lane = tid & 63, wave = tid >> 6;
    const int d0 = tid * 2, d1 = tid * 2 + 1;

    int tot0 = 0, tot1 = 0;
    for (int c = 0; c < NCH; ++c) {
        tot0 += HIST2[(seg * NCH + c) * SEG + d0];
        tot1 += HIST2[(seg * NCH + c) * SEG + d1];
    }
    // entry-count prefix
    int s = tot0 + tot1;
    int incl = s, t;
    t = __shfl_up(incl, 1);  if (lane >= 1)  incl += t;
    t = __shfl_up(incl, 2);  if (lane >= 2)  incl += t;
    t = __shfl_up(incl, 4);  if (lane >= 4)  incl += t;
    t = __shfl_up(incl, 8);  if (lane >= 8)  incl += t;
    t = __shfl_up(incl, 16); if (lane >= 16) incl += t;
    t = __shfl_up(incl, 32); if (lane >= 32) incl += t;
    if (lane == 63) wsum[wave] = incl;
    // chunk-count prefix
    const int nch0 = (tot0 + CHUNK - 1) / CHUNK, nch1 = (tot1 + CHUNK - 1) / CHUNK;
    int s2 = nch0 + nch1;
    int incl2 = s2;
    t = __shfl_up(incl2, 1);  if (lane >= 1)  incl2 += t;
    t = __shfl_up(incl2, 2);  if (lane >= 2)  incl2 += t;
    t = __shfl_up(incl2, 4);  if (lane >= 4)  incl2 += t;
    t = __shfl_up(incl2, 8);  if (lane >= 8)  incl2 += t;
    t = __shfl_up(incl2, 16); if (lane >= 16) incl2 += t;
    t = __shfl_up(incl2, 32); if (lane >= 32) incl2 += t;
    if (lane == 63) wsum2[wave] = incl2;
    __syncthreads();
    int woff = 0, woff2 = 0;
    #pragma unroll
    for (int w = 0; w < 4; ++w) if (w < wave) { woff += wsum[w]; woff2 += wsum2[w]; }
    const int excl  = woff + incl - s;
    const int excl2 = woff2 + incl2 - s2;

    OFFS[seg * SEG + d0] = excl;
    OFFS[seg * SEG + d1] = excl + tot0;
    LEN[seg * SEG + d0] = tot0;
    LEN[seg * SEG + d1] = tot1;

    int run0 = excl, run1 = excl + tot0;
    for (int c = 0; c < NCH; ++c) {
        int i0 = (seg * NCH + c) * SEG + d0;
        CHOFF[i0] = run0;     run0 += HIST2[i0];
        CHOFF[i0 + 1] = run1; run1 += HIST2[i0 + 1];
    }

    int qb = excl2;
    for (int c = 0; c < nch0; ++c) Q[seg * QMAX + qb + c] = (d0 << 16) | c;
    qb += nch0;
    for (int c = 0; c < nch1; ++c) Q[seg * QMAX + qb + c] = (d1 << 16) | c;
    if (tid == 255) QCNT[seg] = woff2 + incl2;
}

// ---------------------------------------------------------------------------
// Scatter (LDS atomics only): block = (chunk of 64 b's, seg in 1..3).
// ---------------------------------------------------------------------------
__global__ __launch_bounds__(256) void scatter_kernel(
    const int* __restrict__ CNT, const int* __restrict__ IDX,
    const float* __restrict__ VAL, const int* __restrict__ CHOFF,
    int* __restrict__ BL, float* __restrict__ PV, int* __restrict__ POS)
{
    __shared__ int cur[SEG];
    const int tid = threadIdx.x;
    const int chunk = blockIdx.x;
    const int seg = blockIdx.y + 1;
    cur[tid] = CHOFF[(seg * NCH + chunk) * SEG + tid];
    cur[tid + 256] = CHOFF[(seg * NCH + chunk) * SEG + tid + 256];
    __syncthreads();

    const int wave = tid >> 6, lane = tid & 63;
    #pragma unroll 4
    for (int i = 0; i < 16; ++i) {
        const int b = chunk * 64 + wave * 16 + i;
        const int cnt = CNT[b * 4 + seg];
        if (lane < cnt) {
            const int base = (b * 4 + seg) * CAP;
            int d = IDX[base + lane];
            float v = VAL[base + lane];
            int pos = atomicAdd(&cur[d], 1);          // LDS atomic
            BL[(size_t)(seg - 1) * NBCAP + pos] = b;
            PV[(size_t)(seg - 1) * NBCAP + pos] = v;
            POS[base + lane] = pos;
        }
    }
}

// ---------------------------------------------------------------------------
// R0[b,i] = sum_t val_t * G0[d_t,i]. One wave per b (4 waves/block).
// ---------------------------------------------------------------------------
__global__ __launch_bounds__(256) void r0_sparse(
    const float* __restrict__ G0,
    const int* __restrict__ CNT, const int* __restrict__ IDX,
    const float* __restrict__ VAL, float* __restrict__ R0v)
{
    const int tid = threadIdx.x;
    const int b = blockIdx.x * 4 + (tid >> 6);
    const int lane = tid & 63;
    const int tg = lane >> 4, iq = lane & 15;
    const int cnt = CNT[b * 4];
    const int base = b * 4 * CAP;
    float4 acc = make_float4(0.f, 0.f, 0.f, 0.f);
    for (int t = tg; t < cnt; t += 4) {
        int d = IDX[base + t];
        float v = VAL[base + t];
        float4 g = *(const float4*)&G0[(size_t)d * RK + iq * 4];
        acc.x += v * g.x; acc.y += v * g.y; acc.z += v * g.z; acc.w += v * g.w;
    }
    acc.x += __shfl_xor(acc.x, 16); acc.y += __shfl_xor(acc.y, 16);
    acc.z += __shfl_xor(acc.z, 16); acc.w += __shfl_xor(acc.w, 16);
    acc.x += __shfl_xor(acc.x, 32); acc.y += __shfl_xor(acc.y, 32);
    acc.z += __shfl_xor(acc.z, 32); acc.w += __shfl_xor(acc.w, 32);
    if (tg == 0) *(float4*)&R0v[(size_t)b * RK + iq * 4] = acc;
}

// ---------------------------------------------------------------------------
// Inverted stage, flat work queue: one block per (d, chunk-of-64-entries)
// descriptor. Uniform bounded work per block -> no load-imbalance tail.
// CONTRIB[pos][j] = phi * sum_k tin[b,k] * G[k,d,j]; no atomics.
// ---------------------------------------------------------------------------
template <int NOUT, int EPT>
__global__ __launch_bounds__(256) void inv_stage(
    const float* __restrict__ TIN, const float* __restrict__ G,
    const int* __restrict__ Qs, const int* __restrict__ QCNTs,
    const int* __restrict__ LENs, const int* __restrict__ OFFSs,
    const int* __restrict__ BLs, const float* __restrict__ PVs,
    float* __restrict__ CONTRIB)
{
    constexpr int JL = NOUT / 4;             // j-quad lanes (16 / 8)
    constexpr int NG = 256 / JL;             // entry groups (16 / 32)
    constexpr int CH = NG * EPT;             // entries per chunk = 64
    static_assert(CH == CHUNK, "chunk mismatch");
    __shared__ float gd[64 * NOUT];
    __shared__ float tins[CH * 68];

    if ((int)blockIdx.x >= QCNTs[0]) return;
    const int tid = threadIdx.x;
    const int desc = Qs[blockIdx.x];
    const int d = desc >> 16, cidx = desc & 0xffff;
    const int len = LENs[d];
    const int off0 = OFFSs[d];
    const int ebase = cidx * CH;

    #pragma unroll
    for (int p = 0; p < (64 * NOUT / 4) / 256; ++p) {
        int f = p * 256 + tid;
        int k = f / (NOUT / 4), jj = f % (NOUT / 4);
        *(float4*)&gd[k * NOUT + jj * 4] =
            *(const float4*)&G[((size_t)k * SEG + d) * NOUT + jj * 4];
    }
    #pragma unroll
    for (int p = 0; p < 4; ++p) {
        int f = p * 256 + tid;
        int en = f >> 4, c4 = (f & 15) * 4;
        int eidx = ebase + en;
        int brow = (eidx < len) ? BLs[off0 + eidx] : 0;
        *(float4*)&tins[en * 68 + c4] =
            *(const float4*)&TIN[(size_t)brow * RK + c4];
    }
    __syncthreads();

    const int egp = tid / JL, jq = tid % JL;
    float4 a[EPT];
    #pragma unroll
    for (int q = 0; q < EPT; ++q) a[q] = make_float4(0.f, 0.f, 0.f, 0.f);

    #pragma unroll 4
    for (int k = 0; k < 64; ++k) {
        float4 gv = *(const float4*)&gd[k * NOUT + jq * 4];
        #pragma unroll
        for (int q = 0; q < EPT; ++q) {
            float tv = tins[(egp * EPT + q) * 68 + k];
            a[q].x += tv * gv.x; a[q].y += tv * gv.y;
            a[q].z += tv * gv.z; a[q].w += tv * gv.w;
        }
    }
    #pragma unroll
    for (int q = 0; q < EPT; ++q) {
        const int ie = ebase + egp * EPT + q;
        if (ie < len) {
            float ph = PVs[off0 + ie];
            float4 v = make_float4(ph * a[q].x, ph * a[q].y,
                                   ph * a[q].z, ph * a[q].w);
            *(float4*)&CONTRIB[(size_t)(off0 + ie) * NOUT + jq * 4] = v;
        }
    }
}

// ---------------------------------------------------------------------------
// Gather (owner-writes): tout[b,j] = sum_{t<cnt} CONTRIB[POS[b,t]][j].
// ---------------------------------------------------------------------------
template <int NOUT>
__global__ __launch_bounds__(256) void gather_kernel(
    const int* __restrict__ CNT, const int* __restrict__ POS,
    const float* __restrict__ CONTRIB, float* __restrict__ TOUT, int seg)
{
    constexpr int JL = NOUT / 4;
    constexpr int TG = 64 / JL;
    const int tid = threadIdx.x;
    const int b = blockIdx.x * 4 + (tid >> 6);
    const int lane = tid & 63;
    const int tg = lane / JL, iq = lane % JL;
    const int cnt = CNT[b * 4 + seg];
    const int base = (b * 4 + seg) * CAP;
    float4 acc = make_float4(0.f, 0.f, 0.f, 0.f);
    for (int t = tg; t < cnt; t += TG) {
        int pos = POS[base + t];
        float4 v = *(const float4*)&CONTRIB[(size_t)pos * NOUT + iq * 4];
        acc.x += v.x; acc.y += v.y; acc.z += v.z; acc.w += v.w;
    }
    #pragma unroll
    for (int off = JL; off < 64; off <<= 1) {
        acc.x += __shfl_xor(acc.x, off); acc.y += __shfl_xor(acc.y, off);
        acc.z += __shfl_xor(acc.z, off); acc.w += __shfl_xor(acc.w, off);
    }
    if (tg == 0) *(float4*)&TOUT[(size_t)b * NOUT + iq * 4] = acc;
}

// ---------------------------------------------------------------------------
extern "C" void kernel_launch(void* const* d_in, const int* in_sizes, int n_in,
                              void* d_out, int out_size, void* d_ws, size_t ws_size,
                              hipStream_t stream)
{
    const float* X  = (const float*)d_in[0];
    const float* C  = (const float*)d_in[1];
    const float* LS = (const float*)d_in[2];
    const float* G0 = (const float*)d_in[3];
    const float* G1 = (const float*)d_in[4];
    const float* G2 = (const float*)d_in[5];
    const float* G3 = (const float*)d_in[6];
    float* out = (float*)d_out;

    // E (33.5 MB, dead after rowselect) and CONTRIB (<=67 MB) share region.
    // Total footprint ~90.3 MB (< R4's proven 91.3 MB).
    char* ws = (char*)d_ws;
    float* E       = (float*)ws;
    float* CONTRIB = (float*)ws;
    size_t o = (size_t)NBCAP * RK * 4;                              // 67 MB
    int*   CNT   = (int*)(ws + o);   o += (size_t)NB * 4 * 4;       // 64 KB
    int*   IDX   = (int*)(ws + o);   o += (size_t)NB * 4 * CAP * 4; // 4 MB
    float* VAL   = (float*)(ws + o); o += (size_t)NB * 4 * CAP * 4; // 4 MB
    int*   POS   = (int*)(ws + o);   o += (size_t)NB * 4 * CAP * 4; // 4 MB
    int*   HIST2 = (int*)(ws + o);   o += (size_t)4 * NCH * SEG * 4;// 512 KB
    int*   CHOFF = (int*)(ws + o);   o += (size_t)4 * NCH * SEG * 4;// 512 KB
    int*   OFFS  = (int*)(ws + o);   o += 4 * SEG * 4;              // 8 KB
    int*   LEN   = (int*)(ws + o);   o += 4 * SEG * 4;              // 8 KB
    int*   Q     = (int*)(ws + o);   o += (size_t)4 * QMAX * 4;     // 74 KB
    int*   QCNT  = (int*)(ws + o);   o += 64;
    int*   BL    = (int*)(ws + o);   o += (size_t)3 * NBCAP * 4;    // 3 MB
    float* PV    = (float*)(ws + o); o += (size_t)3 * NBCAP * 4;    // 3 MB
    float* R0v   = (float*)(ws + o); o += (size_t)NB * RK * 4;      // 1 MB
    float* t1    = (float*)(ws + o); o += (size_t)NB * RK * 4;      // 1 MB
    float* t2    = (float*)(ws + o); o += (size_t)NB * RK * 4;      // 1 MB

    hipMemsetAsync(HIST2, 0, (size_t)4 * NCH * SEG * 4, stream);

    e_gemm<<<dim3(NCEN / 64, NB / 64), 256, 0, stream>>>(X, C, LS, E);
    rowselect<<<NB, 256, 0, stream>>>(E, CNT, IDX, VAL, HIST2);
    scan2_kernel<<<4, 256, 0, stream>>>(HIST2, OFFS, LEN, CHOFF, Q, QCNT);
    scatter_kernel<<<dim3(NCH, 3), 256, 0, stream>>>(CNT, IDX, VAL, CHOFF, BL, PV, POS);
    r0_sparse<<<NB / 4, 256, 0, stream>>>(G0, CNT, IDX, VAL, R0v);

    inv_stage<64, 4><<<QMAX, 256, 0, stream>>>(
        R0v, G1, Q + 1 * QMAX, QCNT + 1, LEN + SEG, OFFS + SEG, BL, PV, CONTRIB);
    gather_kernel<64><<<NB / 4, 256, 0, stream>>>(CNT, POS, CONTRIB, t1, 1);

    inv_stage<64, 4><<<QMAX, 256, 0, stream>>>(
        t1, G2, Q + 2 * QMAX, QCNT + 2, LEN + 2 * SEG, OFFS + 2 * SEG,
        BL + (size_t)NBCAP, PV + (size_t)NBCAP, CONTRIB);
    gather_kernel<64><<<NB / 4, 256, 0, stream>>>(CNT, POS, CONTRIB, t2, 2);

    inv_stage<32, 2><<<QMAX, 256, 0, stream>>>(
        t2, G3, Q + 3 * QMAX, QCNT + 3, LEN + 3 * SEG, OFFS + 3 * SEG,
        BL + (size_t)2 * NBCAP, PV + (size_t)2 * NBCAP, CONTRIB);
    gather_kernel<32><<<NB / 4, 256, 0, stream>>>(CNT, POS, CONTRIB, out, 3);
}